// Round 4
// baseline (275.080 us; speedup 1.0000x reference)
//
#include <hip/hip_runtime.h>
#include <hip/hip_bf16.h>

#define SLOPE 0.2f
#define NPB 64            // nodes per sort bucket
#define CAP 2048          // sortedSrc slots per bucket (mean 1638, 10 sigma)
#define SUBCAP 384        // pairW slots per (bucket, blockgroup) window
#define MAXBUCK 1024
#define EPB 4096          // edges per scatter chunk
#define XF1B 512          // xform1 blocks (merged launch)
#define PPARTS 16         // pool partials per graph

typedef _Float16 f16x8  __attribute__((ext_vector_type(8)));
typedef float    f32x4  __attribute__((ext_vector_type(4)));
typedef unsigned u32;
typedef unsigned u32x4  __attribute__((ext_vector_type(4)));

__device__ __forceinline__ float lrelu(float v) { return fmaxf(v, SLOPE * v); }

__device__ __forceinline__ float lane_bcast(float v, int k) {
    return __int_as_float(__builtin_amdgcn_readlane(__float_as_int(v), k));
}

// packed f16 leaky-relu: max(v, 0.2*v) elementwise
__device__ __forceinline__ f16x8 lrelu8(f16x8 v) {
    f16x8 s = v * (_Float16)SLOPE;
#if __has_builtin(__builtin_elementwise_max)
    return __builtin_elementwise_max(v, s);
#else
    f16x8 r;
#pragma unroll
    for (int i = 0; i < 8; ++i) r[i] = v[i] > s[i] ? v[i] : s[i];
    return r;
#endif
}

// f32 -> (hi, lo) f16 split; hi+lo reproduces v to ~2^-22.
__device__ __forceinline__ void split_f16(float v, _Float16& h, _Float16& l) {
    h = (_Float16)v;
    l = (_Float16)(v - (float)h);
}
__device__ __forceinline__ u32 pack_f16(_Float16 a, _Float16 b) {
    return (u32)__builtin_bit_cast(unsigned short, a) |
           ((u32)__builtin_bit_cast(unsigned short, b) << 16);
}

// ---------------------------------------------------------------------------
// Merged launch: blocks [0,nCntB) counting-sort a 4096-edge chunk into 8-way
// sub-cursor bucket windows of pairW. Histogram phase uses 4 wave-privatized
// LDS copies (R16: 299K bank-conflict cycles with one shared copy).
// Blocks [nCntB,..): conv1 node transform (f16 out).
// ---------------------------------------------------------------------------
__global__ void __launch_bounds__(256) scatter_xform1_kernel(
    const int* __restrict__ srcI, const int* __restrict__ dstI,
    int* __restrict__ cursor, u32* __restrict__ pairW,
    int E, int nNodes, int nBuck, int nCntB,
    const float* __restrict__ x,
    const float* __restrict__ W1, const float* __restrict__ b1,
    _Float16* __restrict__ Ph, _Float16* __restrict__ Qh)
{
    if (blockIdx.x < nCntB) {
        __shared__ int cnt4[4][MAXBUCK];     // wave-privatized histogram
        __shared__ int base[MAXBUCK];
        const int tid = threadIdx.x;
        const int wv  = tid >> 6;
        const int j   = blockIdx.x & 7;      // sub-cursor group (~XCD)
        const int e0 = blockIdx.x * EPB;
        const int e1 = min(e0 + EPB, E);
        const int n4 = (e1 - e0) >> 2;       // vectorizable quads
        const int4* d4 = (const int4*)(dstI + e0);
        const int4* s4 = (const int4*)(srcI + e0);

        for (int b = tid; b < nBuck; b += 256) {
            cnt4[0][b] = 0; cnt4[1][b] = 0; cnt4[2][b] = 0; cnt4[3][b] = 0;
        }
        __syncthreads();
        int* mycnt = cnt4[wv];
        for (int i = tid; i < n4; i += 256) {
            const int4 d = d4[i];
            atomicAdd(&mycnt[d.x >> 6], 1);
            atomicAdd(&mycnt[d.y >> 6], 1);
            atomicAdd(&mycnt[d.z >> 6], 1);
            atomicAdd(&mycnt[d.w >> 6], 1);
        }
        for (int e = e0 + (n4 << 2) + tid; e < e1; e += 256)   // tail
            atomicAdd(&mycnt[dstI[e] >> 6], 1);
        __syncthreads();
        for (int b = tid; b < nBuck; b += 256) {
            const int c = (cnt4[0][b] + cnt4[1][b]) + (cnt4[2][b] + cnt4[3][b]);
            base[b] = (c > 0)
                ? ((b * 8 + j) * SUBCAP + min(atomicAdd(&cursor[b * 8 + j], c), SUBCAP))
                : 0;
        }
        __syncthreads();
        for (int b = tid; b < nBuck; b += 256) cnt4[0][b] = 0;
        __syncthreads();
        int* scnt = cnt4[0];
        for (int i = tid; i < n4; i += 256) {
            const int4 d = d4[i];
            const int4 s = s4[i];
            {
                const int b = d.x >> 6;
                const int loc = atomicAdd(&scnt[b], 1);
                pairW[min(base[b] + loc, (b * 8 + j + 1) * SUBCAP - 1)] =
                    ((u32)s.x << 6) | (u32)(d.x & (NPB - 1));
            }
            {
                const int b = d.y >> 6;
                const int loc = atomicAdd(&scnt[b], 1);
                pairW[min(base[b] + loc, (b * 8 + j + 1) * SUBCAP - 1)] =
                    ((u32)s.y << 6) | (u32)(d.y & (NPB - 1));
            }
            {
                const int b = d.z >> 6;
                const int loc = atomicAdd(&scnt[b], 1);
                pairW[min(base[b] + loc, (b * 8 + j + 1) * SUBCAP - 1)] =
                    ((u32)s.z << 6) | (u32)(d.z & (NPB - 1));
            }
            {
                const int b = d.w >> 6;
                const int loc = atomicAdd(&scnt[b], 1);
                pairW[min(base[b] + loc, (b * 8 + j + 1) * SUBCAP - 1)] =
                    ((u32)s.w << 6) | (u32)(d.w & (NPB - 1));
            }
        }
        for (int e = e0 + (n4 << 2) + tid; e < e1; e += 256) { // tail
            const int d = dstI[e];
            const int b = d >> 6;
            const int loc = atomicAdd(&scnt[b], 1);
            pairW[min(base[b] + loc, (b * 8 + j + 1) * SUBCAP - 1)] =
                ((u32)srcI[e] << 6) | (u32)(d & (NPB - 1));
        }
        return;
    }
    const int lane = threadIdx.x & 63;
    const int wave = ((blockIdx.x - nCntB) * 256 + threadIdx.x) >> 6;
    const int nw   = (XF1B * 256) >> 6;

    float wd[6], wb[6];
#pragma unroll
    for (int r = 0; r < 6; ++r) {
        wb[r] = W1[(6 + r) * 64 + lane];
        wd[r] = W1[r * 64 + lane] - wb[r];
    }
    const float bb = b1[lane];
    for (int i = wave; i < nNodes; i += nw) {
        const float* xr = x + (size_t)i * 6;
        float p = bb, q = 0.f;
#pragma unroll
        for (int r = 0; r < 6; ++r) {
            float xv = xr[r];
            p = fmaf(xv, wd[r], p);
            q = fmaf(xv, wb[r], q);
        }
        Ph[(size_t)i * 64 + lane] = (_Float16)p;
        Qh[(size_t)i * 64 + lane] = (_Float16)q;
    }
}

// One block per bucket: compact the 8 sub-windows into LDS once (u32x4
// global loads), then count + scatter passes run entirely LDS->LDS.
__global__ void __launch_bounds__(256) bucket_sort_kernel(
    const u32* __restrict__ pairW, const int* __restrict__ cursor,
    int2* __restrict__ rowInfo, int* __restrict__ sortedSrc, int nNodes)
{
    __shared__ u32 pairLds[CAP];
    __shared__ int nodeCnt[NPB];
    __shared__ int nodeCur[NPB];
    __shared__ int wcS[8];
    __shared__ int wBase[9];
    const int b   = blockIdx.x;
    const int n0  = b * NPB;
    const int n1  = min(n0 + NPB, nNodes);
    const int tid = threadIdx.x;

    if (tid < NPB) nodeCnt[tid] = 0;
    if (tid < 8) wcS[tid] = min(cursor[b * 8 + tid], SUBCAP);
    __syncthreads();
    if (tid == 0) {
        int acc = 0;
#pragma unroll
        for (int jj = 0; jj < 8; ++jj) { wBase[jj] = acc; acc += wcS[jj]; }
        wBase[8] = acc;
    }
    __syncthreads();

    // compact sub-windows into pairLds (vector global loads, LDS stores)
#pragma unroll
    for (int jj = 0; jj < 8; ++jj) {
        const int w0 = (b * 8 + jj) * SUBCAP;
        const int wc = wcS[jj];
        const int d0 = wBase[jj];
        const int nv = wc >> 2;
        const u32x4* p4 = (const u32x4*)(pairW + w0);
        for (int i = tid; i < nv; i += 256) {
            const u32x4 v = p4[i];
            pairLds[d0 + i * 4 + 0] = v[0];
            pairLds[d0 + i * 4 + 1] = v[1];
            pairLds[d0 + i * 4 + 2] = v[2];
            pairLds[d0 + i * 4 + 3] = v[3];
        }
        for (int i = (nv << 2) + tid; i < wc; i += 256)
            pairLds[d0 + i] = pairW[w0 + i];
    }
    __syncthreads();

    const int total = wBase[8];
    for (int i = tid; i < total; i += 256)           // LDS->LDS count
        atomicAdd(&nodeCnt[pairLds[i] & (NPB - 1)], 1);
    __syncthreads();
    if (tid < 64) {                       // wave 0: prefix scan of 64 counts
        const int c = nodeCnt[tid];
        int inc = c;
#pragma unroll
        for (int off = 1; off < 64; off <<= 1) {
            int t = __shfl_up(inc, off);
            if (tid >= off) inc += t;
        }
        const int st = b * CAP + inc - c; // exclusive, bucket-window-local
        nodeCur[tid] = st;
        if (tid < n1 - n0) rowInfo[n0 + tid] = make_int2(st, c);
    }
    __syncthreads();
    for (int i = tid; i < total; i += 256) {         // LDS read, global write
        const u32 w = pairLds[i];
        const int pos = atomicAdd(&nodeCur[w & (NPB - 1)], 1);
        sortedSrc[pos] = (int)(w >> 6);
    }
}

// ---------------------------------------------------------------------------
// Node transform for conv2 (f16 in/out, VALU readlane -- R13-proven):
//   P[i] = A_i @ (W3top - W3bot) + b3;  Q[j] = A_j @ W3bot
// ---------------------------------------------------------------------------
__global__ void __launch_bounds__(256) node_xform2_kernel(
    const _Float16* __restrict__ B1h,
    const float* __restrict__ W3, const float* __restrict__ b3,
    _Float16* __restrict__ Ph, _Float16* __restrict__ Qh, int nNodes)
{
    const int lane = threadIdx.x & 63;
    const int wave = (blockIdx.x * blockDim.x + threadIdx.x) >> 6;
    const int nw   = (gridDim.x * blockDim.x) >> 6;

    float wd[64], wb[64];
#pragma unroll
    for (int k = 0; k < 64; ++k) {
        wb[k] = W3[(64 + k) * 64 + lane];
        wd[k] = W3[k * 64 + lane] - wb[k];
    }
    const float bb = b3[lane];

    for (int i = wave; i < nNodes; i += nw) {
        const float a = (float)B1h[(size_t)i * 64 + lane];
        float p0 = bb, p1 = 0.f, p2 = 0.f, p3 = 0.f;
        float q0 = 0.f, q1 = 0.f, q2 = 0.f, q3 = 0.f;
#pragma unroll
        for (int k = 0; k < 64; k += 4) {
            float a0 = lane_bcast(a, k);
            float a1 = lane_bcast(a, k + 1);
            float a2 = lane_bcast(a, k + 2);
            float a3 = lane_bcast(a, k + 3);
            p0 = fmaf(a0, wd[k],     p0);  q0 = fmaf(a0, wb[k],     q0);
            p1 = fmaf(a1, wd[k + 1], p1);  q1 = fmaf(a1, wb[k + 1], q1);
            p2 = fmaf(a2, wd[k + 2], p2);  q2 = fmaf(a2, wb[k + 2], q2);
            p3 = fmaf(a3, wd[k + 3], p3);  q3 = fmaf(a3, wb[k + 3], q3);
        }
        Ph[(size_t)i * 64 + lane] = (_Float16)((p0 + p1) + (p2 + p3));
        Qh[(size_t)i * 64 + lane] = (_Float16)((q0 + q1) + (q2 + q3));
    }
}

// ---------------------------------------------------------------------------
// CSR MFMA edge+aggregate (f16), FOUR ADJACENT nodes (two pairs) per wave
// iteration. R0-R3 evidence: latency-bound (MfmaUtil 20 / VALUBusy 36 / HBM
// 12%, no saturated pipe); cross-iteration Q prefetch spills (R1/R2);
// cheap-front prefetch is neutral (R3, gather latency dominates). Fix: widen
// WITHIN the iteration -- all 24 loads (8 idx, 16 Q-gathers, 8 P) issue
// before any compute, doubling memory-level parallelism per dependency
// chain; 128 MFMAs of compute cover the later gathers. No loop-carried
// vectors (the R0-proven no-spill pattern, just wider). Per-pair tail loops
// keep deg>32 padding at pair granularity.
// Pad slots replicate edge deg-1 -> unmasked max fold. f16 output rows.
// Floor: FETCH ~48 MB = 8 XCDs x 6.4 MB Qh compulsory L2 misses.
// C/D layout: row=(lane>>4)*4+reg, col=lane&15 (m89-verified).
// ---------------------------------------------------------------------------

#define COMPUTE32(PA, PB, QA0, QA1, QB0, QB1, M0, M1, M2, M3)                  \
  {                                                                            \
    const f16x8 A00_ = lrelu8((PA) + (QA0));                                   \
    const f16x8 A01_ = lrelu8((PB) + (QA1));                                   \
    const f16x8 A10_ = lrelu8((PA) + (QB0));                                   \
    const f16x8 A11_ = lrelu8((PB) + (QB1));                                   \
    _Pragma("unroll")                                                          \
    for (int nt_ = 0; nt_ < 4; ++nt_) {                                        \
      const f16x8 wh0_ = __builtin_bit_cast(f16x8, wlds[nt_ * 2][lane]);       \
      const f16x8 wh1_ = __builtin_bit_cast(f16x8, wlds[nt_ * 2 + 1][lane]);   \
      const f16x8 wl0_ = __builtin_bit_cast(f16x8, wlds[8 + nt_ * 2][lane]);   \
      const f16x8 wl1_ = __builtin_bit_cast(f16x8, wlds[8 + nt_ * 2 + 1][lane]); \
      f32x4 a_; a_[0] = a_[1] = a_[2] = a_[3] = bc[nt_];                       \
      a_ = __builtin_amdgcn_mfma_f32_16x16x32_f16(A00_, wl0_, a_, 0, 0, 0);    \
      a_ = __builtin_amdgcn_mfma_f32_16x16x32_f16(A00_, wh0_, a_, 0, 0, 0);    \
      a_ = __builtin_amdgcn_mfma_f32_16x16x32_f16(A01_, wl1_, a_, 0, 0, 0);    \
      a_ = __builtin_amdgcn_mfma_f32_16x16x32_f16(A01_, wh1_, a_, 0, 0, 0);    \
      f32x4 c_; c_[0] = c_[1] = c_[2] = c_[3] = bc[nt_];                       \
      c_ = __builtin_amdgcn_mfma_f32_16x16x32_f16(A10_, wl0_, c_, 0, 0, 0);    \
      c_ = __builtin_amdgcn_mfma_f32_16x16x32_f16(A10_, wh0_, c_, 0, 0, 0);    \
      c_ = __builtin_amdgcn_mfma_f32_16x16x32_f16(A11_, wl1_, c_, 0, 0, 0);    \
      c_ = __builtin_amdgcn_mfma_f32_16x16x32_f16(A11_, wh1_, c_, 0, 0, 0);    \
      float m_ = (nt_ == 0) ? (M0) : (nt_ == 1) ? (M1) : (nt_ == 2) ? (M2) : (M3); \
      m_ = fmaxf(fmaxf(fmaxf(a_[0], a_[1]), a_[2]), fmaxf(a_[3], m_));         \
      m_ = fmaxf(fmaxf(fmaxf(c_[0], c_[1]), c_[2]), fmaxf(c_[3], m_));         \
      if (nt_ == 0) (M0) = m_; else if (nt_ == 1) (M1) = m_;                   \
      else if (nt_ == 2) (M2) = m_; else (M3) = m_;                            \
    }                                                                          \
  }

#define REDUCE_STORE(M0, M1, M2, M3, NODE, DEG)                                \
  {                                                                            \
    (M0) = fmaxf((M0), __shfl_xor((M0), 16)); (M0) = fmaxf((M0), __shfl_xor((M0), 32)); \
    (M1) = fmaxf((M1), __shfl_xor((M1), 16)); (M1) = fmaxf((M1), __shfl_xor((M1), 32)); \
    (M2) = fmaxf((M2), __shfl_xor((M2), 16)); (M2) = fmaxf((M2), __shfl_xor((M2), 32)); \
    (M3) = fmaxf((M3), __shfl_xor((M3), 16)); (M3) = fmaxf((M3), __shfl_xor((M3), 32)); \
    const float sel_ = (q < 2) ? ((q == 0) ? (M0) : (M1))                      \
                               : ((q == 2) ? (M2) : (M3));                     \
    outB[(size_t)(NODE) * 64 + q * 16 + cn] =                                  \
        (_Float16)(((DEG) > 0) ? lrelu(sel_) : 0.0f);                          \
  }

__global__ void __launch_bounds__(256) edge_agg_mfma_kernel(
    const _Float16* __restrict__ Ph, const _Float16* __restrict__ Qh,
    const int2* __restrict__ rowInfo, const int* __restrict__ sortedSrc,
    const float* __restrict__ W, const float* __restrict__ b,
    _Float16* __restrict__ outB, int nNodes)
{
    __shared__ u32x4 wlds[16][64];   // 16 KB: frag f (0-7 wh, 8-15 wl), per lane

    const int tid  = threadIdx.x;
    const int lane = tid & 63;
    const int cn   = lane & 15;   // A: edge slot; B/C: column
    const int q    = lane >> 4;   // quad
    const int wv   = tid >> 6;    // wave in block
    const int wave = (blockIdx.x * 256 + tid) >> 6;
    const int nw   = (gridDim.x * 256) >> 6;

    // cooperative weight-fragment init (frag f: isLo=f>=8, nt=(f&7)>>1, ks=f&1)
#pragma unroll
    for (int i = 0; i < 4; ++i) {
        const int f    = wv + i * 4;
        const int isLo = f >> 3;
        const int g    = f & 7;
        const int nt   = g >> 1;
        const int ks   = g & 1;
        u32x4 d;
#pragma unroll
        for (int p = 0; p < 4; ++p) {
            float w0 = W[(ks * 32 + q * 8 + 2 * p)     * 64 + nt * 16 + cn];
            float w1 = W[(ks * 32 + q * 8 + 2 * p + 1) * 64 + nt * 16 + cn];
            _Float16 h0, l0, h1, l1;
            split_f16(w0, h0, l0);
            split_f16(w1, h1, l1);
            d[p] = isLo ? pack_f16(l0, l1) : pack_f16(h0, h1);
        }
        wlds[f][lane] = d;
    }
    float bc[4];
#pragma unroll
    for (int nt = 0; nt < 4; ++nt) bc[nt] = b[nt * 16 + cn];
    __syncthreads();

    const u32 nClamp = (u32)(nNodes - 1);
    const int nQuads = (nNodes + 3) >> 2;

    for (int t = wave; t < nQuads; t += nw) {
        const int n1 = 4 * t;
        const int n2 = n1 + 1, n3 = n1 + 2, n4 = n1 + 3;
        const bool has2 = (n2 < nNodes);
        const bool has3 = (n3 < nNodes);
        const bool has4 = (n4 < nNodes);

        // quad rowInfo: 4 adjacent int2 -> two 16B loads
        const int2 ri1 = rowInfo[n1];
        const int2 ri2 = has2 ? rowInfo[n2] : make_int2(ri1.x, 0);
        const int2 ri3 = has3 ? rowInfo[n3] : make_int2(ri1.x, 0);
        const int2 ri4 = has4 ? rowInfo[n4] : make_int2(ri1.x, 0);
        const int rs1 = __builtin_amdgcn_readfirstlane(ri1.x);
        const int dg1 = __builtin_amdgcn_readfirstlane(ri1.y);
        const int rs2 = __builtin_amdgcn_readfirstlane(ri2.x);
        const int dg2 = __builtin_amdgcn_readfirstlane(ri2.y);
        const int rs3 = __builtin_amdgcn_readfirstlane(ri3.x);
        const int dg3 = __builtin_amdgcn_readfirstlane(ri3.y);
        const int rs4 = __builtin_amdgcn_readfirstlane(ri4.x);
        const int dg4 = __builtin_amdgcn_readfirstlane(ri4.y);
        const int d1c = max(dg1, 1) - 1;
        const int d2c = max(dg2, 1) - 1;
        const int d3c = max(dg3, 1) - 1;
        const int d4c = max(dg4, 1) - 1;

        // ---- issue ALL index loads (4 nodes x 2 groups) ----
        u32 sA1 = (u32)sortedSrc[rs1 + min(cn,      d1c)];
        u32 sB1 = (u32)sortedSrc[rs1 + min(16 + cn, d1c)];
        u32 sA2 = (u32)sortedSrc[rs2 + min(cn,      d2c)];
        u32 sB2 = (u32)sortedSrc[rs2 + min(16 + cn, d2c)];
        u32 sA3 = (u32)sortedSrc[rs3 + min(cn,      d3c)];
        u32 sB3 = (u32)sortedSrc[rs3 + min(16 + cn, d3c)];
        u32 sA4 = (u32)sortedSrc[rs4 + min(cn,      d4c)];
        u32 sB4 = (u32)sortedSrc[rs4 + min(16 + cn, d4c)];
        sA1 = min(sA1, nClamp); sB1 = min(sB1, nClamp);   // poison guard
        sA2 = min(sA2, nClamp); sB2 = min(sB2, nClamp);
        sA3 = min(sA3, nClamp); sB3 = min(sB3, nClamp);
        sA4 = min(sA4, nClamp); sB4 = min(sB4, nClamp);

        // ---- issue ALL Q gathers (16) + P rows (8) ----
        const f16x8* QA1 = (const f16x8*)(Qh + (size_t)sA1 * 64);
        const f16x8* QB1 = (const f16x8*)(Qh + (size_t)sB1 * 64);
        const f16x8* QA2 = (const f16x8*)(Qh + (size_t)sA2 * 64);
        const f16x8* QB2 = (const f16x8*)(Qh + (size_t)sB2 * 64);
        const f16x8* QA3 = (const f16x8*)(Qh + (size_t)sA3 * 64);
        const f16x8* QB3 = (const f16x8*)(Qh + (size_t)sB3 * 64);
        const f16x8* QA4 = (const f16x8*)(Qh + (size_t)sA4 * 64);
        const f16x8* QB4 = (const f16x8*)(Qh + (size_t)sB4 * 64);
        const f16x8 qA1a = QA1[q], qA1b = QA1[4 + q];
        const f16x8 qB1a = QB1[q], qB1b = QB1[4 + q];
        const f16x8 qA2a = QA2[q], qA2b = QA2[4 + q];
        const f16x8 qB2a = QB2[q], qB2b = QB2[4 + q];
        const f16x8 qA3a = QA3[q], qA3b = QA3[4 + q];
        const f16x8 qB3a = QB3[q], qB3b = QB3[4 + q];
        const f16x8 qA4a = QA4[q], qA4b = QA4[4 + q];
        const f16x8 qB4a = QB4[q], qB4b = QB4[4 + q];
        const f16x8* P1 = (const f16x8*)(Ph + (size_t)n1 * 64);
        const f16x8* P2 = (const f16x8*)(Ph + (size_t)(has2 ? n2 : n1) * 64);
        const f16x8* P3 = (const f16x8*)(Ph + (size_t)(has3 ? n3 : n1) * 64);
        const f16x8* P4 = (const f16x8*)(Ph + (size_t)(has4 ? n4 : n1) * 64);
        const f16x8 p1A = P1[q], p1B = P1[4 + q];
        const f16x8 p2A = P2[q], p2B = P2[4 + q];
        const f16x8 p3A = P3[q], p3B = P3[4 + q];
        const f16x8 p4A = P4[q], p4B = P4[4 + q];

        // ---- compute group 0 of all 4 nodes (late gathers covered) ----
        float m10 = -INFINITY, m11 = -INFINITY, m12 = -INFINITY, m13 = -INFINITY;
        float m20 = -INFINITY, m21 = -INFINITY, m22 = -INFINITY, m23 = -INFINITY;
        float m30 = -INFINITY, m31 = -INFINITY, m32 = -INFINITY, m33 = -INFINITY;
        float m40 = -INFINITY, m41 = -INFINITY, m42 = -INFINITY, m43 = -INFINITY;
        if (dg1 > 0) COMPUTE32(p1A, p1B, qA1a, qA1b, qB1a, qB1b, m10, m11, m12, m13);
        if (dg2 > 0) COMPUTE32(p2A, p2B, qA2a, qA2b, qB2a, qB2b, m20, m21, m22, m23);
        if (dg3 > 0) COMPUTE32(p3A, p3B, qA3a, qA3b, qB3a, qB3b, m30, m31, m32, m33);
        if (dg4 > 0) COMPUTE32(p4A, p4B, qA4a, qA4b, qB4a, qB4b, m40, m41, m42, m43);

        // ---- tail groups >= 32, pair granularity ----
        const int gmax12 = max(dg1, dg2);
        for (int g0 = 32; g0 < gmax12; g0 += 32) {
            u32 eA1 = min((u32)sortedSrc[rs1 + min(g0 + cn,      d1c)], nClamp);
            u32 eB1 = min((u32)sortedSrc[rs1 + min(g0 + 16 + cn, d1c)], nClamp);
            u32 eA2 = min((u32)sortedSrc[rs2 + min(g0 + cn,      d2c)], nClamp);
            u32 eB2 = min((u32)sortedSrc[rs2 + min(g0 + 16 + cn, d2c)], nClamp);
            const f16x8* EA1 = (const f16x8*)(Qh + (size_t)eA1 * 64);
            const f16x8* EB1 = (const f16x8*)(Qh + (size_t)eB1 * 64);
            const f16x8* EA2 = (const f16x8*)(Qh + (size_t)eA2 * 64);
            const f16x8* EB2 = (const f16x8*)(Qh + (size_t)eB2 * 64);
            const f16x8 gA1a = EA1[q], gA1b = EA1[4 + q];
            const f16x8 gB1a = EB1[q], gB1b = EB1[4 + q];
            const f16x8 gA2a = EA2[q], gA2b = EA2[4 + q];
            const f16x8 gB2a = EB2[q], gB2b = EB2[4 + q];
            if (g0 < dg1) COMPUTE32(p1A, p1B, gA1a, gA1b, gB1a, gB1b, m10, m11, m12, m13);
            if (g0 < dg2) COMPUTE32(p2A, p2B, gA2a, gA2b, gB2a, gB2b, m20, m21, m22, m23);
        }
        const int gmax34 = max(dg3, dg4);
        for (int g0 = 32; g0 < gmax34; g0 += 32) {
            u32 eA3 = min((u32)sortedSrc[rs3 + min(g0 + cn,      d3c)], nClamp);
            u32 eB3 = min((u32)sortedSrc[rs3 + min(g0 + 16 + cn, d3c)], nClamp);
            u32 eA4 = min((u32)sortedSrc[rs4 + min(g0 + cn,      d4c)], nClamp);
            u32 eB4 = min((u32)sortedSrc[rs4 + min(g0 + 16 + cn, d4c)], nClamp);
            const f16x8* EA3 = (const f16x8*)(Qh + (size_t)eA3 * 64);
            const f16x8* EB3 = (const f16x8*)(Qh + (size_t)eB3 * 64);
            const f16x8* EA4 = (const f16x8*)(Qh + (size_t)eA4 * 64);
            const f16x8* EB4 = (const f16x8*)(Qh + (size_t)eB4 * 64);
            const f16x8 gA3a = EA3[q], gA3b = EA3[4 + q];
            const f16x8 gB3a = EB3[q], gB3b = EB3[4 + q];
            const f16x8 gA4a = EA4[q], gA4b = EA4[4 + q];
            const f16x8 gB4a = EB4[q], gB4b = EB4[4 + q];
            if (g0 < dg3) COMPUTE32(p3A, p3B, gA3a, gA3b, gB3a, gB3b, m30, m31, m32, m33);
            if (g0 < dg4) COMPUTE32(p4A, p4B, gA4a, gA4b, gB4a, gB4b, m40, m41, m42, m43);
        }

        // ---- cross-quad max butterflies + stores (f16) ----
        REDUCE_STORE(m10, m11, m12, m13, n1, dg1);
        if (has2) REDUCE_STORE(m20, m21, m22, m23, n2, dg2);
        if (has3) REDUCE_STORE(m30, m31, m32, m33, n3, dg3);
        if (has4) REDUCE_STORE(m40, m41, m42, m43, n4, dg4);
    }
}

__device__ __forceinline__ int lower_bound_i(const int* __restrict__ a, int n, int key)
{
    int lo = 0, hi = n;
    while (lo < hi) {
        int mid = (lo + hi) >> 1;
        if (a[mid] < key) lo = mid + 1; else hi = mid;
    }
    return lo;
}

// PPARTS blocks per graph (1024 blocks, streaming-BW bound), f16 input.
__global__ void __launch_bounds__(256) pool_kernel(
    const _Float16* __restrict__ Bh, const int* __restrict__ batch,
    float* __restrict__ gpart, int nNodes)
{
    const int gid  = blockIdx.x / PPARTS;
    const int part = blockIdx.x % PPARTS;
    const int c    = threadIdx.x & 63;
    const int wid  = threadIdx.x >> 6;

    const int s = lower_bound_i(batch, nNodes, gid);
    const int e = lower_bound_i(batch, nNodes, gid + 1);
    const int len = e - s;
    const int ps = s + (len * part) / PPARTS;
    const int pe = s + (len * (part + 1)) / PPARTS;

    float sum = 0.f, mx = -INFINITY;
    for (int n = ps + wid; n < pe; n += 4) {
        float v = (float)Bh[(size_t)n * 64 + c];
        sum += v;
        mx = fmaxf(mx, v);
    }
    __shared__ float ssum[4][64];
    __shared__ float smax[4][64];
    ssum[wid][c] = sum;
    smax[wid][c] = mx;
    __syncthreads();
    if (wid == 0) {
        sum = (ssum[0][c] + ssum[1][c]) + (ssum[2][c] + ssum[3][c]);
        mx  = fmaxf(fmaxf(smax[0][c], smax[1][c]), fmaxf(smax[2][c], smax[3][c]));
        float* row = gpart + (size_t)blockIdx.x * 132;
        row[c]      = sum;
        row[64 + c] = mx;
        if (c == 0) row[128] = (float)(pe - ps);
    }
}

// One wave per graph: combine PPARTS pool partials, then classifier head.
__global__ void __launch_bounds__(64) cls_kernel(
    const float* __restrict__ gpart,
    const float* __restrict__ Wc1, const float* __restrict__ bc1,
    const float* __restrict__ Wc2, const float* __restrict__ bc2,
    float* __restrict__ out)
{
    __shared__ float g[128];
    const int gid = blockIdx.x;
    const int c   = threadIdx.x;

    float s = 0.f, m = -INFINITY, cnt = 0.f;
#pragma unroll
    for (int p = 0; p < PPARTS; ++p) {
        const float* row = gpart + (size_t)(gid * PPARTS + p) * 132;
        s += row[c];
        m = fmaxf(m, row[64 + c]);
        cnt += row[128];
    }
    g[c]      = s / fmaxf(cnt, 1.0f);
    g[64 + c] = (cnt > 0.f) ? m : 0.0f;
    __syncthreads();

    float t = bc1[c];
#pragma unroll 8
    for (int k = 0; k < 128; ++k) t = fmaf(g[k], Wc1[k * 64 + c], t);
    t = lrelu(t);
    float p = t * Wc2[c];
#pragma unroll
    for (int off = 32; off > 0; off >>= 1) p += __shfl_down(p, off);
    if (c == 0) out[gid] = p + bc2[0];
}

static inline size_t align_up(size_t v, size_t a) { return (v + a - 1) & ~(a - 1); }

extern "C" void kernel_launch(void* const* d_in, const int* in_sizes, int n_in,
                              void* d_out, int out_size, void* d_ws, size_t ws_size,
                              hipStream_t stream)
{
    const float* x     = (const float*)d_in[0];
    const int*   ei    = (const int*)d_in[1];
    const int*   batch = (const int*)d_in[2];
    const float* W1  = (const float*)d_in[3];
    const float* b1  = (const float*)d_in[4];
    const float* W2  = (const float*)d_in[5];
    const float* b2  = (const float*)d_in[6];
    const float* W3  = (const float*)d_in[7];
    const float* b3  = (const float*)d_in[8];
    const float* W4  = (const float*)d_in[9];
    const float* b4  = (const float*)d_in[10];
    const float* Wc1 = (const float*)d_in[11];
    const float* bc1 = (const float*)d_in[12];
    const float* Wc2 = (const float*)d_in[13];
    const float* bc2 = (const float*)d_in[14];
    float* out = (float*)d_out;

    const int nNodes  = in_sizes[0] / 6;
    const int E       = in_sizes[1] / 2;
    const int nGraphs = out_size;
    const int* srcI = ei;
    const int* dstI = ei + E;
    const int nBuck = (nNodes + NPB - 1) / NPB;
    const int nCntB = (E + EPB - 1) / EPB;

    // workspace carve-up (256B-aligned)
    char* wsp = (char*)d_ws;
    size_t off = 0;
    int*  cursor    = (int*)(wsp + off);   off = align_up(off + (size_t)MAXBUCK * 8 * 4, 256);
    int2* rowInfo   = (int2*)(wsp + off);  off = align_up(off + (size_t)nNodes * 8, 256);
    int*  sortedSrc = (int*)(wsp + off);   off = align_up(off + (size_t)nBuck * CAP * 4, 256);
    u32*  pairW     = (u32*)(wsp + off);   off = align_up(off + (size_t)nBuck * 8 * SUBCAP * 4, 256);
    const size_t nFeat = (size_t)nNodes * 64;
    _Float16* Ph   = (_Float16*)(wsp + off);  off = align_up(off + nFeat * 2, 256);
    _Float16* Qh   = (_Float16*)(wsp + off);  off = align_up(off + nFeat * 2, 256);
    _Float16* B1h  = (_Float16*)(wsp + off);  off = align_up(off + nFeat * 2, 256);
    _Float16* B2h  = (_Float16*)(wsp + off);  off = align_up(off + nFeat * 2, 256);
    float*    gpart= (float*)(wsp + off);     off = align_up(off + (size_t)nGraphs * PPARTS * 132 * 4, 256);
    (void)ws_size;

    // ---- CSR build (vectorized scatter, privatized hist) + conv1 transform ----
    (void)hipMemsetAsync(cursor, 0, (size_t)nBuck * 8 * 4, stream);
    scatter_xform1_kernel<<<nCntB + XF1B, 256, 0, stream>>>(
        srcI, dstI, cursor, pairW, E, nNodes, nBuck, nCntB, x, W1, b1, Ph, Qh);
    bucket_sort_kernel<<<nBuck, 256, 0, stream>>>(pairW, cursor, rowInfo,
                                                  sortedSrc, nNodes);

    // ---- conv1 edge+agg ----
    edge_agg_mfma_kernel<<<2048, 256, 0, stream>>>(Ph, Qh, rowInfo, sortedSrc,
                                                   W2, b2, B1h, nNodes);
    // ---- conv2 ----
    node_xform2_kernel<<<2048, 256, 0, stream>>>(B1h, W3, b3, Ph, Qh, nNodes);
    edge_agg_mfma_kernel<<<2048, 256, 0, stream>>>(Ph, Qh, rowInfo, sortedSrc,
                                                   W4, b4, B2h, nNodes);

    // ---- pooling + classifier head ----
    pool_kernel<<<nGraphs * PPARTS, 256, 0, stream>>>(B2h, batch, gpart, nNodes);
    cls_kernel<<<nGraphs, 64, 0, stream>>>(gpart, Wc1, bc1, Wc2, bc2, out);
}

// Round 5
// 261.428 us; speedup vs baseline: 1.0522x; 1.0522x over previous
//
#include <hip/hip_runtime.h>
#include <hip/hip_bf16.h>

#define SLOPE 0.2f
#define NPB 64            // nodes per sort bucket
#define CAP 2048          // sortedSrc slots per bucket (mean 1638, 10 sigma)
#define SUBCAP 384        // pairW slots per (bucket, blockgroup) window
#define MAXBUCK 1024
#define EPB 4096          // edges per scatter chunk
#define XF1B 512          // xform1 blocks (merged launch)
#define PPARTS 16         // pool partials per graph

typedef _Float16 f16x8  __attribute__((ext_vector_type(8)));
typedef float    f32x4  __attribute__((ext_vector_type(4)));
typedef unsigned u32;
typedef unsigned u32x4  __attribute__((ext_vector_type(4)));

__device__ __forceinline__ float lrelu(float v) { return fmaxf(v, SLOPE * v); }

// packed f16 leaky-relu: max(v, 0.2*v) elementwise
__device__ __forceinline__ f16x8 lrelu8(f16x8 v) {
    f16x8 s = v * (_Float16)SLOPE;
#if __has_builtin(__builtin_elementwise_max)
    return __builtin_elementwise_max(v, s);
#else
    f16x8 r;
#pragma unroll
    for (int i = 0; i < 8; ++i) r[i] = v[i] > s[i] ? v[i] : s[i];
    return r;
#endif
}

// f32 -> (hi, lo) f16 split; hi+lo reproduces v to ~2^-22.
__device__ __forceinline__ void split_f16(float v, _Float16& h, _Float16& l) {
    h = (_Float16)v;
    l = (_Float16)(v - (float)h);
}
__device__ __forceinline__ u32 pack_f16(_Float16 a, _Float16 b) {
    return (u32)__builtin_bit_cast(unsigned short, a) |
           ((u32)__builtin_bit_cast(unsigned short, b) << 16);
}

// ---------------------------------------------------------------------------
// Merged launch: blocks [0,nCntB) counting-sort a 4096-edge chunk into 8-way
// sub-cursor bucket windows of pairW. Histogram phase uses 4 wave-privatized
// LDS copies (R16: 299K bank-conflict cycles with one shared copy).
// Blocks [nCntB,..): conv1 node transform (f16 out).
// ---------------------------------------------------------------------------
__global__ void __launch_bounds__(256) scatter_xform1_kernel(
    const int* __restrict__ srcI, const int* __restrict__ dstI,
    int* __restrict__ cursor, u32* __restrict__ pairW,
    int E, int nNodes, int nBuck, int nCntB,
    const float* __restrict__ x,
    const float* __restrict__ W1, const float* __restrict__ b1,
    _Float16* __restrict__ Ph, _Float16* __restrict__ Qh)
{
    if (blockIdx.x < nCntB) {
        __shared__ int cnt4[4][MAXBUCK];     // wave-privatized histogram
        __shared__ int base[MAXBUCK];
        const int tid = threadIdx.x;
        const int wv  = tid >> 6;
        const int j   = blockIdx.x & 7;      // sub-cursor group (~XCD)
        const int e0 = blockIdx.x * EPB;
        const int e1 = min(e0 + EPB, E);
        const int n4 = (e1 - e0) >> 2;       // vectorizable quads
        const int4* d4 = (const int4*)(dstI + e0);
        const int4* s4 = (const int4*)(srcI + e0);

        for (int b = tid; b < nBuck; b += 256) {
            cnt4[0][b] = 0; cnt4[1][b] = 0; cnt4[2][b] = 0; cnt4[3][b] = 0;
        }
        __syncthreads();
        int* mycnt = cnt4[wv];
        for (int i = tid; i < n4; i += 256) {
            const int4 d = d4[i];
            atomicAdd(&mycnt[d.x >> 6], 1);
            atomicAdd(&mycnt[d.y >> 6], 1);
            atomicAdd(&mycnt[d.z >> 6], 1);
            atomicAdd(&mycnt[d.w >> 6], 1);
        }
        for (int e = e0 + (n4 << 2) + tid; e < e1; e += 256)   // tail
            atomicAdd(&mycnt[dstI[e] >> 6], 1);
        __syncthreads();
        for (int b = tid; b < nBuck; b += 256) {
            const int c = (cnt4[0][b] + cnt4[1][b]) + (cnt4[2][b] + cnt4[3][b]);
            base[b] = (c > 0)
                ? ((b * 8 + j) * SUBCAP + min(atomicAdd(&cursor[b * 8 + j], c), SUBCAP))
                : 0;
        }
        __syncthreads();
        for (int b = tid; b < nBuck; b += 256) cnt4[0][b] = 0;
        __syncthreads();
        int* scnt = cnt4[0];
        for (int i = tid; i < n4; i += 256) {
            const int4 d = d4[i];
            const int4 s = s4[i];
            {
                const int b = d.x >> 6;
                const int loc = atomicAdd(&scnt[b], 1);
                pairW[min(base[b] + loc, (b * 8 + j + 1) * SUBCAP - 1)] =
                    ((u32)s.x << 6) | (u32)(d.x & (NPB - 1));
            }
            {
                const int b = d.y >> 6;
                const int loc = atomicAdd(&scnt[b], 1);
                pairW[min(base[b] + loc, (b * 8 + j + 1) * SUBCAP - 1)] =
                    ((u32)s.y << 6) | (u32)(d.y & (NPB - 1));
            }
            {
                const int b = d.z >> 6;
                const int loc = atomicAdd(&scnt[b], 1);
                pairW[min(base[b] + loc, (b * 8 + j + 1) * SUBCAP - 1)] =
                    ((u32)s.z << 6) | (u32)(d.z & (NPB - 1));
            }
            {
                const int b = d.w >> 6;
                const int loc = atomicAdd(&scnt[b], 1);
                pairW[min(base[b] + loc, (b * 8 + j + 1) * SUBCAP - 1)] =
                    ((u32)s.w << 6) | (u32)(d.w & (NPB - 1));
            }
        }
        for (int e = e0 + (n4 << 2) + tid; e < e1; e += 256) { // tail
            const int d = dstI[e];
            const int b = d >> 6;
            const int loc = atomicAdd(&scnt[b], 1);
            pairW[min(base[b] + loc, (b * 8 + j + 1) * SUBCAP - 1)] =
                ((u32)srcI[e] << 6) | (u32)(d & (NPB - 1));
        }
        return;
    }
    const int lane = threadIdx.x & 63;
    const int wave = ((blockIdx.x - nCntB) * 256 + threadIdx.x) >> 6;
    const int nw   = (XF1B * 256) >> 6;

    float wd[6], wb[6];
#pragma unroll
    for (int r = 0; r < 6; ++r) {
        wb[r] = W1[(6 + r) * 64 + lane];
        wd[r] = W1[r * 64 + lane] - wb[r];
    }
    const float bb = b1[lane];
    for (int i = wave; i < nNodes; i += nw) {
        const float* xr = x + (size_t)i * 6;
        float p = bb, q = 0.f;
#pragma unroll
        for (int r = 0; r < 6; ++r) {
            float xv = xr[r];
            p = fmaf(xv, wd[r], p);
            q = fmaf(xv, wb[r], q);
        }
        Ph[(size_t)i * 64 + lane] = (_Float16)p;
        Qh[(size_t)i * 64 + lane] = (_Float16)q;
    }
}

// One block per bucket: compact the 8 sub-windows into LDS once (u32x4
// global loads), then count + scatter passes run entirely LDS->LDS.
// R5: BOTH passes wave-privatized (4 histogram copies + 4 cursor copies;
// order within a node's window is irrelevant -- max aggregation), cutting
// same-address LDS-atomic serialization ~4x.
__global__ void __launch_bounds__(256) bucket_sort_kernel(
    const u32* __restrict__ pairW, const int* __restrict__ cursor,
    int2* __restrict__ rowInfo, int* __restrict__ sortedSrc, int nNodes)
{
    __shared__ u32 pairLds[CAP];
    __shared__ int nodeCnt4[4][NPB];
    __shared__ int nodeCur4[4][NPB];
    __shared__ int wcS[8];
    __shared__ int wBase[9];
    const int b   = blockIdx.x;
    const int n0  = b * NPB;
    const int n1  = min(n0 + NPB, nNodes);
    const int tid = threadIdx.x;
    const int wv  = tid >> 6;

    if (tid < NPB) {
        nodeCnt4[0][tid] = 0; nodeCnt4[1][tid] = 0;
        nodeCnt4[2][tid] = 0; nodeCnt4[3][tid] = 0;
    }
    if (tid < 8) wcS[tid] = min(cursor[b * 8 + tid], SUBCAP);
    __syncthreads();
    if (tid == 0) {
        int acc = 0;
#pragma unroll
        for (int jj = 0; jj < 8; ++jj) { wBase[jj] = acc; acc += wcS[jj]; }
        wBase[8] = acc;
    }
    __syncthreads();

    // compact sub-windows into pairLds (vector global loads, LDS stores)
#pragma unroll
    for (int jj = 0; jj < 8; ++jj) {
        const int w0 = (b * 8 + jj) * SUBCAP;
        const int wc = wcS[jj];
        const int d0 = wBase[jj];
        const int nv = wc >> 2;
        const u32x4* p4 = (const u32x4*)(pairW + w0);
        for (int i = tid; i < nv; i += 256) {
            const u32x4 v = p4[i];
            pairLds[d0 + i * 4 + 0] = v[0];
            pairLds[d0 + i * 4 + 1] = v[1];
            pairLds[d0 + i * 4 + 2] = v[2];
            pairLds[d0 + i * 4 + 3] = v[3];
        }
        for (int i = (nv << 2) + tid; i < wc; i += 256)
            pairLds[d0 + i] = pairW[w0 + i];
    }
    __syncthreads();

    const int total = wBase[8];
    for (int i = tid; i < total; i += 256)           // LDS->LDS count (priv)
        atomicAdd(&nodeCnt4[wv][pairLds[i] & (NPB - 1)], 1);
    __syncthreads();
    if (tid < 64) {                       // wave 0: prefix scan of 64 counts
        const int c0 = nodeCnt4[0][tid], c1 = nodeCnt4[1][tid];
        const int c2 = nodeCnt4[2][tid], c3 = nodeCnt4[3][tid];
        const int c = (c0 + c1) + (c2 + c3);
        int inc = c;
#pragma unroll
        for (int off = 1; off < 64; off <<= 1) {
            int t = __shfl_up(inc, off);
            if (tid >= off) inc += t;
        }
        const int st = b * CAP + inc - c; // exclusive, bucket-window-local
        nodeCur4[0][tid] = st;            // per-wave cursor bases
        nodeCur4[1][tid] = st + c0;
        nodeCur4[2][tid] = st + c0 + c1;
        nodeCur4[3][tid] = st + c0 + c1 + c2;
        if (tid < n1 - n0) rowInfo[n0 + tid] = make_int2(st, c);
    }
    __syncthreads();
    for (int i = tid; i < total; i += 256) {         // LDS read, global write
        const u32 w = pairLds[i];
        const int pos = atomicAdd(&nodeCur4[wv][w & (NPB - 1)], 1);
        sortedSrc[pos] = (int)(w >> 6);
    }
}

// ---------------------------------------------------------------------------
// Node transform for conv2 as MFMA GEMM (R5): the old readlane-VALU version
// was ~192 VALU ops/node/lane (issue-bound, est 25-35us). Same math on the
// matrix pipe: A = B1h rows (16 sequential nodes/wave, coalesced), weights
// split hi/lo f16 (the edge_agg-proven precision scheme), 32 MFMAs per 16
// nodes. Output tiles nt 0-3 -> P = A@(W3top-W3bot)+b3, nt 4-7 -> Q=A@W3bot.
// A layout: row=lane&15, k=(lane>>4)*8+j. C/D: row=(lane>>4)*4+reg,
// col=lane&15 (m89-verified).
// ---------------------------------------------------------------------------
__global__ void __launch_bounds__(256) node_xform2_mfma_kernel(
    const _Float16* __restrict__ B1h,
    const float* __restrict__ W3, const float* __restrict__ b3,
    _Float16* __restrict__ Ph, _Float16* __restrict__ Qh, int nNodes)
{
    __shared__ u32x4 wlds[32][64];   // 32 KB: frag f (0-15 hi, 16-31 lo)

    const int tid  = threadIdx.x;
    const int lane = tid & 63;
    const int cn   = lane & 15;
    const int q    = lane >> 4;
    const int wv   = tid >> 6;
    const int wave = (blockIdx.x * 256 + tid) >> 6;
    const int nw   = (gridDim.x * 256) >> 6;

    // frag f: isLo=f>=16, g=f&15, nt=g>>1 (0-7), ks=g&1
#pragma unroll
    for (int i = 0; i < 8; ++i) {
        const int f    = wv + i * 4;
        const int isLo = f >> 4;
        const int g    = f & 15;
        const int nt   = g >> 1;
        const int ks   = g & 1;
        const int col  = (nt & 3) * 16 + cn;
        u32x4 d;
#pragma unroll
        for (int p = 0; p < 4; ++p) {
            const int k0 = ks * 32 + q * 8 + 2 * p;
            float w0, w1;
            if (nt < 4) {   // P weights: W3top - W3bot
                w0 = W3[k0 * 64 + col]       - W3[(64 + k0) * 64 + col];
                w1 = W3[(k0 + 1) * 64 + col] - W3[(64 + k0 + 1) * 64 + col];
            } else {        // Q weights: W3bot
                w0 = W3[(64 + k0) * 64 + col];
                w1 = W3[(64 + k0 + 1) * 64 + col];
            }
            _Float16 h0, l0, h1, l1;
            split_f16(w0, h0, l0);
            split_f16(w1, h1, l1);
            d[p] = isLo ? pack_f16(l0, l1) : pack_f16(h0, h1);
        }
        wlds[f][lane] = d;
    }
    float bcv[4];
#pragma unroll
    for (int nt = 0; nt < 4; ++nt) bcv[nt] = b3[nt * 16 + cn];
    __syncthreads();

    const int nGrp = (nNodes + 15) >> 4;
    for (int t = wave; t < nGrp; t += nw) {
        const int n0 = t << 4;
        const int rA = min(n0 + cn, nNodes - 1);
        const f16x8* Arow = (const f16x8*)(B1h + (size_t)rA * 64);
        const f16x8 A0 = Arow[q];      // k 0..31 slice (quad-local 8)
        const f16x8 A1 = Arow[4 + q];  // k 32..63 slice

        f32x4 acc0, acc1, acc2, acc3, acc4, acc5, acc6, acc7;
#define NT_TILE(ACC, NT, INI)                                                  \
        {                                                                      \
            const f16x8 wh0 = __builtin_bit_cast(f16x8, wlds[(NT) * 2][lane]); \
            const f16x8 wh1 = __builtin_bit_cast(f16x8, wlds[(NT) * 2 + 1][lane]); \
            const f16x8 wl0 = __builtin_bit_cast(f16x8, wlds[16 + (NT) * 2][lane]); \
            const f16x8 wl1 = __builtin_bit_cast(f16x8, wlds[16 + (NT) * 2 + 1][lane]); \
            f32x4 a_; a_[0] = a_[1] = a_[2] = a_[3] = (INI);                   \
            a_ = __builtin_amdgcn_mfma_f32_16x16x32_f16(A0, wl0, a_, 0, 0, 0); \
            a_ = __builtin_amdgcn_mfma_f32_16x16x32_f16(A0, wh0, a_, 0, 0, 0); \
            a_ = __builtin_amdgcn_mfma_f32_16x16x32_f16(A1, wl1, a_, 0, 0, 0); \
            a_ = __builtin_amdgcn_mfma_f32_16x16x32_f16(A1, wh1, a_, 0, 0, 0); \
            ACC = a_;                                                          \
        }
        NT_TILE(acc0, 0, bcv[0]); NT_TILE(acc1, 1, bcv[1]);
        NT_TILE(acc2, 2, bcv[2]); NT_TILE(acc3, 3, bcv[3]);
        NT_TILE(acc4, 4, 0.0f);   NT_TILE(acc5, 5, 0.0f);
        NT_TILE(acc6, 6, 0.0f);   NT_TILE(acc7, 7, 0.0f);
#undef NT_TILE

        const int rowLim = nNodes - n0;
#pragma unroll
        for (int j = 0; j < 4; ++j) {
            const int r = 4 * q + j;
            if (r < rowLim) {
                _Float16* Pr = Ph + (size_t)(n0 + r) * 64;
                _Float16* Qr = Qh + (size_t)(n0 + r) * 64;
                Pr[cn]      = (_Float16)acc0[j];
                Pr[16 + cn] = (_Float16)acc1[j];
                Pr[32 + cn] = (_Float16)acc2[j];
                Pr[48 + cn] = (_Float16)acc3[j];
                Qr[cn]      = (_Float16)acc4[j];
                Qr[16 + cn] = (_Float16)acc5[j];
                Qr[32 + cn] = (_Float16)acc6[j];
                Qr[48 + cn] = (_Float16)acc7[j];
            }
        }
    }
}

// ---------------------------------------------------------------------------
// CSR MFMA edge+aggregate (f16), TWO ADJACENT nodes per wave: rowInfo pair is
// one int4 load; the pair's sortedSrc windows are contiguous (same bucket) ->
// coalesced index stream. R0-exact chassis (VGPR 60, 8 waves/SIMD): R1-R4
// proved every pipelining/widening variant crosses the 64-VGPR occupancy
// cliff and loses more TLP than the MLP buys.
// Pad slots replicate edge deg-1 -> unmasked max fold. f16 output rows.
// Floor: FETCH ~48 MB = 8 XCDs x 6.4 MB Qh compulsory L2 misses.
// C/D layout: row=(lane>>4)*4+reg, col=lane&15 (m89-verified).
// ---------------------------------------------------------------------------
__global__ void __launch_bounds__(256) edge_agg_mfma_kernel(
    const _Float16* __restrict__ Ph, const _Float16* __restrict__ Qh,
    const int2* __restrict__ rowInfo, const int* __restrict__ sortedSrc,
    const float* __restrict__ W, const float* __restrict__ b,
    _Float16* __restrict__ outB, int nNodes)
{
    __shared__ u32x4 wlds[16][64];   // 16 KB: frag f (0-7 wh, 8-15 wl), per lane

    const int tid  = threadIdx.x;
    const int lane = tid & 63;
    const int cn   = lane & 15;   // A: edge slot; B/C: column
    const int q    = lane >> 4;   // quad
    const int wv   = tid >> 6;    // wave in block
    const int wave = (blockIdx.x * 256 + tid) >> 6;
    const int nw   = (gridDim.x * 256) >> 6;

    // cooperative weight-fragment init (frag f: isLo=f>=8, nt=(f&7)>>1, ks=f&1)
#pragma unroll
    for (int i = 0; i < 4; ++i) {
        const int f    = wv + i * 4;
        const int isLo = f >> 3;
        const int g    = f & 7;
        const int nt   = g >> 1;
        const int ks   = g & 1;
        u32x4 d;
#pragma unroll
        for (int p = 0; p < 4; ++p) {
            float w0 = W[(ks * 32 + q * 8 + 2 * p)     * 64 + nt * 16 + cn];
            float w1 = W[(ks * 32 + q * 8 + 2 * p + 1) * 64 + nt * 16 + cn];
            _Float16 h0, l0, h1, l1;
            split_f16(w0, h0, l0);
            split_f16(w1, h1, l1);
            d[p] = isLo ? pack_f16(l0, l1) : pack_f16(h0, h1);
        }
        wlds[f][lane] = d;
    }
    float bc[4];
#pragma unroll
    for (int nt = 0; nt < 4; ++nt) bc[nt] = b[nt * 16 + cn];
    __syncthreads();

    const u32 nClamp = (u32)(nNodes - 1);
    const int nPairs = (nNodes + 1) >> 1;

    for (int t = wave; t < nPairs; t += nw) {
        const int n1 = 2 * t;
        const int n2 = 2 * t + 1;
        const bool has2 = (n2 < nNodes);

        // adjacent pair: one 16B rowInfo load
        const int2 ri1 = rowInfo[n1];
        const int2 ri2 = has2 ? rowInfo[n2] : make_int2(ri1.x, 0);
        const int rs1  = __builtin_amdgcn_readfirstlane(ri1.x);
        const int deg1 = __builtin_amdgcn_readfirstlane(ri1.y);
        const int rs2  = __builtin_amdgcn_readfirstlane(ri2.x);
        const int deg2 = __builtin_amdgcn_readfirstlane(ri2.y);
        const int d1c = max(deg1, 1) - 1;
        const int d2c = max(deg2, 1) - 1;

        const f16x8* P1 = (const f16x8*)(Ph + (size_t)n1 * 64);
        const f16x8* P2 = (const f16x8*)(Ph + (size_t)(has2 ? n2 : n1) * 64);
        const f16x8 p1A = P1[q], p1B = P1[4 + q];
        const f16x8 p2A = P2[q], p2B = P2[4 + q];

        float m10 = -INFINITY, m11 = -INFINITY, m12 = -INFINITY, m13 = -INFINITY;
        float m20 = -INFINITY, m21 = -INFINITY, m22 = -INFINITY, m23 = -INFINITY;

        const int gmax = max(deg1, deg2);
        for (int g0 = 0; g0 < gmax; g0 += 32) {
            // ---- issue ALL loads (both nodes, both groups) ----
            u32 sA1 = (u32)sortedSrc[rs1 + min(g0 + cn,      d1c)];
            u32 sB1 = (u32)sortedSrc[rs1 + min(g0 + 16 + cn, d1c)];
            u32 sA2 = (u32)sortedSrc[rs2 + min(g0 + cn,      d2c)];
            u32 sB2 = (u32)sortedSrc[rs2 + min(g0 + 16 + cn, d2c)];
            sA1 = min(sA1, nClamp); sB1 = min(sB1, nClamp);   // poison guard
            sA2 = min(sA2, nClamp); sB2 = min(sB2, nClamp);
            const f16x8* QA1 = (const f16x8*)(Qh + (size_t)sA1 * 64);
            const f16x8* QB1 = (const f16x8*)(Qh + (size_t)sB1 * 64);
            const f16x8* QA2 = (const f16x8*)(Qh + (size_t)sA2 * 64);
            const f16x8* QB2 = (const f16x8*)(Qh + (size_t)sB2 * 64);
            const f16x8 qA1a = QA1[q], qA1b = QA1[4 + q];
            const f16x8 qB1a = QB1[q], qB1b = QB1[4 + q];
            const f16x8 qA2a = QA2[q], qA2b = QA2[4 + q];
            const f16x8 qB2a = QB2[q], qB2b = QB2[4 + q];

            // ---- node 1 compute (unmasked fold: pads duplicate edge deg-1) ----
            if (g0 < deg1) {
                const f16x8 A00 = lrelu8(p1A + qA1a);
                const f16x8 A01 = lrelu8(p1B + qA1b);
                const f16x8 A10 = lrelu8(p1A + qB1a);
                const f16x8 A11 = lrelu8(p1B + qB1b);
#pragma unroll
                for (int nt = 0; nt < 4; ++nt) {
                    const f16x8 wh0 = __builtin_bit_cast(f16x8, wlds[nt * 2][lane]);
                    const f16x8 wh1 = __builtin_bit_cast(f16x8, wlds[nt * 2 + 1][lane]);
                    const f16x8 wl0 = __builtin_bit_cast(f16x8, wlds[8 + nt * 2][lane]);
                    const f16x8 wl1 = __builtin_bit_cast(f16x8, wlds[8 + nt * 2 + 1][lane]);
                    f32x4 a; a[0] = a[1] = a[2] = a[3] = bc[nt];
                    a = __builtin_amdgcn_mfma_f32_16x16x32_f16(A00, wl0, a, 0, 0, 0);
                    a = __builtin_amdgcn_mfma_f32_16x16x32_f16(A00, wh0, a, 0, 0, 0);
                    a = __builtin_amdgcn_mfma_f32_16x16x32_f16(A01, wl1, a, 0, 0, 0);
                    a = __builtin_amdgcn_mfma_f32_16x16x32_f16(A01, wh1, a, 0, 0, 0);
                    f32x4 c; c[0] = c[1] = c[2] = c[3] = bc[nt];
                    c = __builtin_amdgcn_mfma_f32_16x16x32_f16(A10, wl0, c, 0, 0, 0);
                    c = __builtin_amdgcn_mfma_f32_16x16x32_f16(A10, wh0, c, 0, 0, 0);
                    c = __builtin_amdgcn_mfma_f32_16x16x32_f16(A11, wl1, c, 0, 0, 0);
                    c = __builtin_amdgcn_mfma_f32_16x16x32_f16(A11, wh1, c, 0, 0, 0);
                    float m = (nt == 0) ? m10 : (nt == 1) ? m11 : (nt == 2) ? m12 : m13;
                    m = fmaxf(m, fmaxf(fmaxf(a[0], a[1]), fmaxf(a[2], a[3])));
                    m = fmaxf(m, fmaxf(fmaxf(c[0], c[1]), fmaxf(c[2], c[3])));
                    if (nt == 0) m10 = m; else if (nt == 1) m11 = m;
                    else if (nt == 2) m12 = m; else m13 = m;
                }
            }
            // ---- node 2 compute ----
            if (g0 < deg2) {
                const f16x8 A00 = lrelu8(p2A + qA2a);
                const f16x8 A01 = lrelu8(p2B + qA2b);
                const f16x8 A10 = lrelu8(p2A + qB2a);
                const f16x8 A11 = lrelu8(p2B + qB2b);
#pragma unroll
                for (int nt = 0; nt < 4; ++nt) {
                    const f16x8 wh0 = __builtin_bit_cast(f16x8, wlds[nt * 2][lane]);
                    const f16x8 wh1 = __builtin_bit_cast(f16x8, wlds[nt * 2 + 1][lane]);
                    const f16x8 wl0 = __builtin_bit_cast(f16x8, wlds[8 + nt * 2][lane]);
                    const f16x8 wl1 = __builtin_bit_cast(f16x8, wlds[8 + nt * 2 + 1][lane]);
                    f32x4 a; a[0] = a[1] = a[2] = a[3] = bc[nt];
                    a = __builtin_amdgcn_mfma_f32_16x16x32_f16(A00, wl0, a, 0, 0, 0);
                    a = __builtin_amdgcn_mfma_f32_16x16x32_f16(A00, wh0, a, 0, 0, 0);
                    a = __builtin_amdgcn_mfma_f32_16x16x32_f16(A01, wl1, a, 0, 0, 0);
                    a = __builtin_amdgcn_mfma_f32_16x16x32_f16(A01, wh1, a, 0, 0, 0);
                    f32x4 c; c[0] = c[1] = c[2] = c[3] = bc[nt];
                    c = __builtin_amdgcn_mfma_f32_16x16x32_f16(A10, wl0, c, 0, 0, 0);
                    c = __builtin_amdgcn_mfma_f32_16x16x32_f16(A10, wh0, c, 0, 0, 0);
                    c = __builtin_amdgcn_mfma_f32_16x16x32_f16(A11, wl1, c, 0, 0, 0);
                    c = __builtin_amdgcn_mfma_f32_16x16x32_f16(A11, wh1, c, 0, 0, 0);
                    float m = (nt == 0) ? m20 : (nt == 1) ? m21 : (nt == 2) ? m22 : m23;
                    m = fmaxf(m, fmaxf(fmaxf(a[0], a[1]), fmaxf(a[2], a[3])));
                    m = fmaxf(m, fmaxf(fmaxf(c[0], c[1]), fmaxf(c[2], c[3])));
                    if (nt == 0) m20 = m; else if (nt == 1) m21 = m;
                    else if (nt == 2) m22 = m; else m23 = m;
                }
            }
        }

        // cross-quad max butterflies + stores (f16)
        m10 = fmaxf(m10, __shfl_xor(m10, 16)); m10 = fmaxf(m10, __shfl_xor(m10, 32));
        m11 = fmaxf(m11, __shfl_xor(m11, 16)); m11 = fmaxf(m11, __shfl_xor(m11, 32));
        m12 = fmaxf(m12, __shfl_xor(m12, 16)); m12 = fmaxf(m12, __shfl_xor(m12, 32));
        m13 = fmaxf(m13, __shfl_xor(m13, 16)); m13 = fmaxf(m13, __shfl_xor(m13, 32));
        float sel1 = (q < 2) ? ((q == 0) ? m10 : m11) : ((q == 2) ? m12 : m13);
        outB[(size_t)n1 * 64 + q * 16 + cn] =
            (_Float16)((deg1 > 0) ? lrelu(sel1) : 0.0f);

        if (has2) {
            m20 = fmaxf(m20, __shfl_xor(m20, 16)); m20 = fmaxf(m20, __shfl_xor(m20, 32));
            m21 = fmaxf(m21, __shfl_xor(m21, 16)); m21 = fmaxf(m21, __shfl_xor(m21, 32));
            m22 = fmaxf(m22, __shfl_xor(m22, 16)); m22 = fmaxf(m22, __shfl_xor(m22, 32));
            m23 = fmaxf(m23, __shfl_xor(m23, 16)); m23 = fmaxf(m23, __shfl_xor(m23, 32));
            float sel2 = (q < 2) ? ((q == 0) ? m20 : m21) : ((q == 2) ? m22 : m23);
            outB[(size_t)n2 * 64 + q * 16 + cn] =
                (_Float16)((deg2 > 0) ? lrelu(sel2) : 0.0f);
        }
    }
}

__device__ __forceinline__ int lower_bound_i(const int* __restrict__ a, int n, int key)
{
    int lo = 0, hi = n;
    while (lo < hi) {
        int mid = (lo + hi) >> 1;
        if (a[mid] < key) lo = mid + 1; else hi = mid;
    }
    return lo;
}

// PPARTS blocks per graph (1024 blocks, streaming-BW bound), f16 input.
__global__ void __launch_bounds__(256) pool_kernel(
    const _Float16* __restrict__ Bh, const int* __restrict__ batch,
    float* __restrict__ gpart, int nNodes)
{
    const int gid  = blockIdx.x / PPARTS;
    const int part = blockIdx.x % PPARTS;
    const int c    = threadIdx.x & 63;
    const int wid  = threadIdx.x >> 6;

    const int s = lower_bound_i(batch, nNodes, gid);
    const int e = lower_bound_i(batch, nNodes, gid + 1);
    const int len = e - s;
    const int ps = s + (len * part) / PPARTS;
    const int pe = s + (len * (part + 1)) / PPARTS;

    float sum = 0.f, mx = -INFINITY;
    for (int n = ps + wid; n < pe; n += 4) {
        float v = (float)Bh[(size_t)n * 64 + c];
        sum += v;
        mx = fmaxf(mx, v);
    }
    __shared__ float ssum[4][64];
    __shared__ float smax[4][64];
    ssum[wid][c] = sum;
    smax[wid][c] = mx;
    __syncthreads();
    if (wid == 0) {
        sum = (ssum[0][c] + ssum[1][c]) + (ssum[2][c] + ssum[3][c]);
        mx  = fmaxf(fmaxf(smax[0][c], smax[1][c]), fmaxf(smax[2][c], smax[3][c]));
        float* row = gpart + (size_t)blockIdx.x * 132;
        row[c]      = sum;
        row[64 + c] = mx;
        if (c == 0) row[128] = (float)(pe - ps);
    }
}

// One wave per graph: combine PPARTS pool partials, then classifier head.
__global__ void __launch_bounds__(64) cls_kernel(
    const float* __restrict__ gpart,
    const float* __restrict__ Wc1, const float* __restrict__ bc1,
    const float* __restrict__ Wc2, const float* __restrict__ bc2,
    float* __restrict__ out)
{
    __shared__ float g[128];
    const int gid = blockIdx.x;
    const int c   = threadIdx.x;

    float s = 0.f, m = -INFINITY, cnt = 0.f;
#pragma unroll
    for (int p = 0; p < PPARTS; ++p) {
        const float* row = gpart + (size_t)(gid * PPARTS + p) * 132;
        s += row[c];
        m = fmaxf(m, row[64 + c]);
        cnt += row[128];
    }
    g[c]      = s / fmaxf(cnt, 1.0f);
    g[64 + c] = (cnt > 0.f) ? m : 0.0f;
    __syncthreads();

    float t = bc1[c];
#pragma unroll 8
    for (int k = 0; k < 128; ++k) t = fmaf(g[k], Wc1[k * 64 + c], t);
    t = lrelu(t);
    float p = t * Wc2[c];
#pragma unroll
    for (int off = 32; off > 0; off >>= 1) p += __shfl_down(p, off);
    if (c == 0) out[gid] = p + bc2[0];
}

static inline size_t align_up(size_t v, size_t a) { return (v + a - 1) & ~(a - 1); }

extern "C" void kernel_launch(void* const* d_in, const int* in_sizes, int n_in,
                              void* d_out, int out_size, void* d_ws, size_t ws_size,
                              hipStream_t stream)
{
    const float* x     = (const float*)d_in[0];
    const int*   ei    = (const int*)d_in[1];
    const int*   batch = (const int*)d_in[2];
    const float* W1  = (const float*)d_in[3];
    const float* b1  = (const float*)d_in[4];
    const float* W2  = (const float*)d_in[5];
    const float* b2  = (const float*)d_in[6];
    const float* W3  = (const float*)d_in[7];
    const float* b3  = (const float*)d_in[8];
    const float* W4  = (const float*)d_in[9];
    const float* b4  = (const float*)d_in[10];
    const float* Wc1 = (const float*)d_in[11];
    const float* bc1 = (const float*)d_in[12];
    const float* Wc2 = (const float*)d_in[13];
    const float* bc2 = (const float*)d_in[14];
    float* out = (float*)d_out;

    const int nNodes  = in_sizes[0] / 6;
    const int E       = in_sizes[1] / 2;
    const int nGraphs = out_size;
    const int* srcI = ei;
    const int* dstI = ei + E;
    const int nBuck = (nNodes + NPB - 1) / NPB;
    const int nCntB = (E + EPB - 1) / EPB;

    // workspace carve-up (256B-aligned)
    char* wsp = (char*)d_ws;
    size_t off = 0;
    int*  cursor    = (int*)(wsp + off);   off = align_up(off + (size_t)MAXBUCK * 8 * 4, 256);
    int2* rowInfo   = (int2*)(wsp + off);  off = align_up(off + (size_t)nNodes * 8, 256);
    int*  sortedSrc = (int*)(wsp + off);   off = align_up(off + (size_t)nBuck * CAP * 4, 256);
    u32*  pairW     = (u32*)(wsp + off);   off = align_up(off + (size_t)nBuck * 8 * SUBCAP * 4, 256);
    const size_t nFeat = (size_t)nNodes * 64;
    _Float16* Ph   = (_Float16*)(wsp + off);  off = align_up(off + nFeat * 2, 256);
    _Float16* Qh   = (_Float16*)(wsp + off);  off = align_up(off + nFeat * 2, 256);
    _Float16* B1h  = (_Float16*)(wsp + off);  off = align_up(off + nFeat * 2, 256);
    _Float16* B2h  = (_Float16*)(wsp + off);  off = align_up(off + nFeat * 2, 256);
    float*    gpart= (float*)(wsp + off);     off = align_up(off + (size_t)nGraphs * PPARTS * 132 * 4, 256);
    (void)ws_size;

    // ---- CSR build (vectorized scatter, privatized hist) + conv1 transform ----
    (void)hipMemsetAsync(cursor, 0, (size_t)nBuck * 8 * 4, stream);
    scatter_xform1_kernel<<<nCntB + XF1B, 256, 0, stream>>>(
        srcI, dstI, cursor, pairW, E, nNodes, nBuck, nCntB, x, W1, b1, Ph, Qh);
    bucket_sort_kernel<<<nBuck, 256, 0, stream>>>(pairW, cursor, rowInfo,
                                                  sortedSrc, nNodes);

    // ---- conv1 edge+agg ----
    edge_agg_mfma_kernel<<<2048, 256, 0, stream>>>(Ph, Qh, rowInfo, sortedSrc,
                                                   W2, b2, B1h, nNodes);
    // ---- conv2: node transform now on the matrix pipe ----
    const int nGrp   = (nNodes + 15) >> 4;          // 16 nodes per wave-group
    const int xf2Blk = (nGrp + 3) >> 2;             // 4 waves per block
    node_xform2_mfma_kernel<<<xf2Blk, 256, 0, stream>>>(B1h, W3, b3, Ph, Qh,
                                                        nNodes);
    edge_agg_mfma_kernel<<<2048, 256, 0, stream>>>(Ph, Qh, rowInfo, sortedSrc,
                                                   W4, b4, B2h, nNodes);

    // ---- pooling + classifier head ----
    pool_kernel<<<nGraphs * PPARTS, 256, 0, stream>>>(B2h, batch, gpart, nNodes);
    cls_kernel<<<nGraphs, 64, 0, stream>>>(gpart, Wc1, bc1, Wc2, bc2, out);
}

// Round 6
// 259.791 us; speedup vs baseline: 1.0589x; 1.0063x over previous
//
#include <hip/hip_runtime.h>
#include <hip/hip_bf16.h>

#define SLOPE 0.2f
#define NPB 64            // nodes per sort bucket
#define CAP 2048          // sortedSrc slots per bucket (mean 1638, 10 sigma)
#define SUBCAP 384        // pairW slots per (bucket, blockgroup) window
#define MAXBUCK 1024
#define EPB 4096          // edges per scatter chunk
#define XF1B 512          // xform1 blocks (merged launch)
#define PPARTS 16         // pool partials per graph

typedef _Float16 f16x8  __attribute__((ext_vector_type(8)));
typedef float    f32x4  __attribute__((ext_vector_type(4)));
typedef unsigned u32;
typedef unsigned u32x4  __attribute__((ext_vector_type(4)));

__device__ __forceinline__ float lrelu(float v) { return fmaxf(v, SLOPE * v); }

// packed f16 leaky-relu: max(v, 0.2*v) elementwise
__device__ __forceinline__ f16x8 lrelu8(f16x8 v) {
    f16x8 s = v * (_Float16)SLOPE;
#if __has_builtin(__builtin_elementwise_max)
    return __builtin_elementwise_max(v, s);
#else
    f16x8 r;
#pragma unroll
    for (int i = 0; i < 8; ++i) r[i] = v[i] > s[i] ? v[i] : s[i];
    return r;
#endif
}

// f32 -> (hi, lo) f16 split; hi+lo reproduces v to ~2^-22.
__device__ __forceinline__ void split_f16(float v, _Float16& h, _Float16& l) {
    h = (_Float16)v;
    l = (_Float16)(v - (float)h);
}
__device__ __forceinline__ u32 pack_f16(_Float16 a, _Float16 b) {
    return (u32)__builtin_bit_cast(unsigned short, a) |
           ((u32)__builtin_bit_cast(unsigned short, b) << 16);
}

// ---------------------------------------------------------------------------
// Merged launch: blocks [0,nCntB) counting-sort a 4096-edge chunk into 8-way
// sub-cursor bucket windows of pairW. Histogram phase uses 4 wave-privatized
// LDS copies (R16: 299K bank-conflict cycles with one shared copy).
// Blocks [nCntB,..): conv1 node transform (f16 out).
// ---------------------------------------------------------------------------
__global__ void __launch_bounds__(256) scatter_xform1_kernel(
    const int* __restrict__ srcI, const int* __restrict__ dstI,
    int* __restrict__ cursor, u32* __restrict__ pairW,
    int E, int nNodes, int nBuck, int nCntB,
    const float* __restrict__ x,
    const float* __restrict__ W1, const float* __restrict__ b1,
    _Float16* __restrict__ Ph, _Float16* __restrict__ Qh)
{
    if (blockIdx.x < nCntB) {
        __shared__ int cnt4[4][MAXBUCK];     // wave-privatized histogram
        __shared__ int base[MAXBUCK];
        const int tid = threadIdx.x;
        const int wv  = tid >> 6;
        const int j   = blockIdx.x & 7;      // sub-cursor group (~XCD)
        const int e0 = blockIdx.x * EPB;
        const int e1 = min(e0 + EPB, E);
        const int n4 = (e1 - e0) >> 2;       // vectorizable quads
        const int4* d4 = (const int4*)(dstI + e0);
        const int4* s4 = (const int4*)(srcI + e0);

        for (int b = tid; b < nBuck; b += 256) {
            cnt4[0][b] = 0; cnt4[1][b] = 0; cnt4[2][b] = 0; cnt4[3][b] = 0;
        }
        __syncthreads();
        int* mycnt = cnt4[wv];
        for (int i = tid; i < n4; i += 256) {
            const int4 d = d4[i];
            atomicAdd(&mycnt[d.x >> 6], 1);
            atomicAdd(&mycnt[d.y >> 6], 1);
            atomicAdd(&mycnt[d.z >> 6], 1);
            atomicAdd(&mycnt[d.w >> 6], 1);
        }
        for (int e = e0 + (n4 << 2) + tid; e < e1; e += 256)   // tail
            atomicAdd(&mycnt[dstI[e] >> 6], 1);
        __syncthreads();
        for (int b = tid; b < nBuck; b += 256) {
            const int c = (cnt4[0][b] + cnt4[1][b]) + (cnt4[2][b] + cnt4[3][b]);
            base[b] = (c > 0)
                ? ((b * 8 + j) * SUBCAP + min(atomicAdd(&cursor[b * 8 + j], c), SUBCAP))
                : 0;
        }
        __syncthreads();
        for (int b = tid; b < nBuck; b += 256) cnt4[0][b] = 0;
        __syncthreads();
        int* scnt = cnt4[0];
        for (int i = tid; i < n4; i += 256) {
            const int4 d = d4[i];
            const int4 s = s4[i];
            {
                const int b = d.x >> 6;
                const int loc = atomicAdd(&scnt[b], 1);
                pairW[min(base[b] + loc, (b * 8 + j + 1) * SUBCAP - 1)] =
                    ((u32)s.x << 6) | (u32)(d.x & (NPB - 1));
            }
            {
                const int b = d.y >> 6;
                const int loc = atomicAdd(&scnt[b], 1);
                pairW[min(base[b] + loc, (b * 8 + j + 1) * SUBCAP - 1)] =
                    ((u32)s.y << 6) | (u32)(d.y & (NPB - 1));
            }
            {
                const int b = d.z >> 6;
                const int loc = atomicAdd(&scnt[b], 1);
                pairW[min(base[b] + loc, (b * 8 + j + 1) * SUBCAP - 1)] =
                    ((u32)s.z << 6) | (u32)(d.z & (NPB - 1));
            }
            {
                const int b = d.w >> 6;
                const int loc = atomicAdd(&scnt[b], 1);
                pairW[min(base[b] + loc, (b * 8 + j + 1) * SUBCAP - 1)] =
                    ((u32)s.w << 6) | (u32)(d.w & (NPB - 1));
            }
        }
        for (int e = e0 + (n4 << 2) + tid; e < e1; e += 256) { // tail
            const int d = dstI[e];
            const int b = d >> 6;
            const int loc = atomicAdd(&scnt[b], 1);
            pairW[min(base[b] + loc, (b * 8 + j + 1) * SUBCAP - 1)] =
                ((u32)srcI[e] << 6) | (u32)(d & (NPB - 1));
        }
        return;
    }
    const int lane = threadIdx.x & 63;
    const int wave = ((blockIdx.x - nCntB) * 256 + threadIdx.x) >> 6;
    const int nw   = (XF1B * 256) >> 6;

    float wd[6], wb[6];
#pragma unroll
    for (int r = 0; r < 6; ++r) {
        wb[r] = W1[(6 + r) * 64 + lane];
        wd[r] = W1[r * 64 + lane] - wb[r];
    }
    const float bb = b1[lane];
    for (int i = wave; i < nNodes; i += nw) {
        const float* xr = x + (size_t)i * 6;
        float p = bb, q = 0.f;
#pragma unroll
        for (int r = 0; r < 6; ++r) {
            float xv = xr[r];
            p = fmaf(xv, wd[r], p);
            q = fmaf(xv, wb[r], q);
        }
        Ph[(size_t)i * 64 + lane] = (_Float16)p;
        Qh[(size_t)i * 64 + lane] = (_Float16)q;
    }
}

// One block per bucket: compact the 8 sub-windows into LDS once, count +
// scan + scatter entirely in LDS (R5: both atomic passes wave-privatized).
// R6: scatter lands in sortLds, then (a) sortedSrc written COALESCED,
// (b) fixedSrc[n*32+i] emitted: pre-padded fixed-stride group-0 index
// windows (slot i = edge min(i,deg-1); node id if deg==0) so edge_agg's
// group-0 index loads need no rowInfo dependency.
__global__ void __launch_bounds__(256) bucket_sort_kernel(
    const u32* __restrict__ pairW, const int* __restrict__ cursor,
    int2* __restrict__ rowInfo, int* __restrict__ sortedSrc,
    int* __restrict__ fixedSrc, int nNodes)
{
    __shared__ u32 pairLds[CAP];
    __shared__ u32 sortLds[CAP];
    __shared__ int nodeCnt4[4][NPB];
    __shared__ int nodeCur4[4][NPB];
    __shared__ int nodeSt[NPB];
    __shared__ int nodeDg[NPB];
    __shared__ int wcS[8];
    __shared__ int wBase[9];
    const int b   = blockIdx.x;
    const int n0  = b * NPB;
    const int n1  = min(n0 + NPB, nNodes);
    const int tid = threadIdx.x;
    const int wv  = tid >> 6;

    if (tid < NPB) {
        nodeCnt4[0][tid] = 0; nodeCnt4[1][tid] = 0;
        nodeCnt4[2][tid] = 0; nodeCnt4[3][tid] = 0;
    }
    if (tid < 8) wcS[tid] = min(cursor[b * 8 + tid], SUBCAP);
    __syncthreads();
    if (tid == 0) {
        int acc = 0;
#pragma unroll
        for (int jj = 0; jj < 8; ++jj) { wBase[jj] = acc; acc += wcS[jj]; }
        wBase[8] = acc;
    }
    __syncthreads();

    // compact sub-windows into pairLds (vector global loads, LDS stores)
#pragma unroll
    for (int jj = 0; jj < 8; ++jj) {
        const int w0 = (b * 8 + jj) * SUBCAP;
        const int wc = wcS[jj];
        const int d0 = wBase[jj];
        const int nv = wc >> 2;
        const u32x4* p4 = (const u32x4*)(pairW + w0);
        for (int i = tid; i < nv; i += 256) {
            const u32x4 v = p4[i];
            pairLds[d0 + i * 4 + 0] = v[0];
            pairLds[d0 + i * 4 + 1] = v[1];
            pairLds[d0 + i * 4 + 2] = v[2];
            pairLds[d0 + i * 4 + 3] = v[3];
        }
        for (int i = (nv << 2) + tid; i < wc; i += 256)
            pairLds[d0 + i] = pairW[w0 + i];
    }
    __syncthreads();

    const int total = wBase[8];
    for (int i = tid; i < total; i += 256)           // LDS->LDS count (priv)
        atomicAdd(&nodeCnt4[wv][pairLds[i] & (NPB - 1)], 1);
    __syncthreads();
    if (tid < 64) {                       // wave 0: prefix scan of 64 counts
        const int c0 = nodeCnt4[0][tid], c1 = nodeCnt4[1][tid];
        const int c2 = nodeCnt4[2][tid], c3 = nodeCnt4[3][tid];
        const int c = (c0 + c1) + (c2 + c3);
        int inc = c;
#pragma unroll
        for (int off = 1; off < 64; off <<= 1) {
            int t = __shfl_up(inc, off);
            if (tid >= off) inc += t;
        }
        const int stl = inc - c;          // exclusive, bucket-LOCAL
        nodeSt[tid] = stl;
        nodeDg[tid] = c;
        nodeCur4[0][tid] = stl;           // per-wave cursor bases (local)
        nodeCur4[1][tid] = stl + c0;
        nodeCur4[2][tid] = stl + c0 + c1;
        nodeCur4[3][tid] = stl + c0 + c1 + c2;
        if (tid < n1 - n0) rowInfo[n0 + tid] = make_int2(b * CAP + stl, c);
    }
    __syncthreads();
    for (int i = tid; i < total; i += 256) {         // LDS->LDS scatter
        const u32 w = pairLds[i];
        const int pos = atomicAdd(&nodeCur4[wv][w & (NPB - 1)], 1);
        sortLds[pos] = w >> 6;
    }
    __syncthreads();
    for (int i = tid; i < total; i += 256)           // coalesced global write
        sortedSrc[b * CAP + i] = (int)sortLds[i];
    // pre-padded fixed-stride group-0 windows (coalesced 128B per node)
    const int nValid = n1 - n0;
    for (int idx = tid; idx < NPB * 32; idx += 256) {
        const int r = idx >> 5;
        const int i = idx & 31;
        if (r < nValid) {
            const int dg = nodeDg[r];
            const u32 v = (dg > 0) ? sortLds[nodeSt[r] + min(i, dg - 1)]
                                   : (u32)(n0 + r);
            fixedSrc[(size_t)(n0 + r) * 32 + i] = (int)v;
        }
    }
}

// ---------------------------------------------------------------------------
// Node transform for conv2 as MFMA GEMM (R5): the old readlane-VALU version
// was ~192 VALU ops/node/lane (issue-bound, est 25-35us). Same math on the
// matrix pipe: A = B1h rows (16 sequential nodes/wave, coalesced), weights
// split hi/lo f16 (the edge_agg-proven precision scheme), 32 MFMAs per 16
// nodes. Output tiles nt 0-3 -> P = A@(W3top-W3bot)+b3, nt 4-7 -> Q=A@W3bot.
// A layout: row=lane&15, k=(lane>>4)*8+j. C/D: row=(lane>>4)*4+reg,
// col=lane&15 (m89-verified).
// ---------------------------------------------------------------------------
__global__ void __launch_bounds__(256) node_xform2_mfma_kernel(
    const _Float16* __restrict__ B1h,
    const float* __restrict__ W3, const float* __restrict__ b3,
    _Float16* __restrict__ Ph, _Float16* __restrict__ Qh, int nNodes)
{
    __shared__ u32x4 wlds[32][64];   // 32 KB: frag f (0-15 hi, 16-31 lo)

    const int tid  = threadIdx.x;
    const int lane = tid & 63;
    const int cn   = lane & 15;
    const int q    = lane >> 4;
    const int wv   = tid >> 6;
    const int wave = (blockIdx.x * 256 + tid) >> 6;
    const int nw   = (gridDim.x * 256) >> 6;

    // frag f: isLo=f>=16, g=f&15, nt=g>>1 (0-7), ks=g&1
#pragma unroll
    for (int i = 0; i < 8; ++i) {
        const int f    = wv + i * 4;
        const int isLo = f >> 4;
        const int g    = f & 15;
        const int nt   = g >> 1;
        const int ks   = g & 1;
        const int col  = (nt & 3) * 16 + cn;
        u32x4 d;
#pragma unroll
        for (int p = 0; p < 4; ++p) {
            const int k0 = ks * 32 + q * 8 + 2 * p;
            float w0, w1;
            if (nt < 4) {   // P weights: W3top - W3bot
                w0 = W3[k0 * 64 + col]       - W3[(64 + k0) * 64 + col];
                w1 = W3[(k0 + 1) * 64 + col] - W3[(64 + k0 + 1) * 64 + col];
            } else {        // Q weights: W3bot
                w0 = W3[(64 + k0) * 64 + col];
                w1 = W3[(64 + k0 + 1) * 64 + col];
            }
            _Float16 h0, l0, h1, l1;
            split_f16(w0, h0, l0);
            split_f16(w1, h1, l1);
            d[p] = isLo ? pack_f16(l0, l1) : pack_f16(h0, h1);
        }
        wlds[f][lane] = d;
    }
    float bcv[4];
#pragma unroll
    for (int nt = 0; nt < 4; ++nt) bcv[nt] = b3[nt * 16 + cn];
    __syncthreads();

    const int nGrp = (nNodes + 15) >> 4;
    for (int t = wave; t < nGrp; t += nw) {
        const int n0 = t << 4;
        const int rA = min(n0 + cn, nNodes - 1);
        const f16x8* Arow = (const f16x8*)(B1h + (size_t)rA * 64);
        const f16x8 A0 = Arow[q];      // k 0..31 slice (quad-local 8)
        const f16x8 A1 = Arow[4 + q];  // k 32..63 slice

        f32x4 acc0, acc1, acc2, acc3, acc4, acc5, acc6, acc7;
#define NT_TILE(ACC, NT, INI)                                                  \
        {                                                                      \
            const f16x8 wh0 = __builtin_bit_cast(f16x8, wlds[(NT) * 2][lane]); \
            const f16x8 wh1 = __builtin_bit_cast(f16x8, wlds[(NT) * 2 + 1][lane]); \
            const f16x8 wl0 = __builtin_bit_cast(f16x8, wlds[16 + (NT) * 2][lane]); \
            const f16x8 wl1 = __builtin_bit_cast(f16x8, wlds[16 + (NT) * 2 + 1][lane]); \
            f32x4 a_; a_[0] = a_[1] = a_[2] = a_[3] = (INI);                   \
            a_ = __builtin_amdgcn_mfma_f32_16x16x32_f16(A0, wl0, a_, 0, 0, 0); \
            a_ = __builtin_amdgcn_mfma_f32_16x16x32_f16(A0, wh0, a_, 0, 0, 0); \
            a_ = __builtin_amdgcn_mfma_f32_16x16x32_f16(A1, wl1, a_, 0, 0, 0); \
            a_ = __builtin_amdgcn_mfma_f32_16x16x32_f16(A1, wh1, a_, 0, 0, 0); \
            ACC = a_;                                                          \
        }
        NT_TILE(acc0, 0, bcv[0]); NT_TILE(acc1, 1, bcv[1]);
        NT_TILE(acc2, 2, bcv[2]); NT_TILE(acc3, 3, bcv[3]);
        NT_TILE(acc4, 4, 0.0f);   NT_TILE(acc5, 5, 0.0f);
        NT_TILE(acc6, 6, 0.0f);   NT_TILE(acc7, 7, 0.0f);
#undef NT_TILE

        const int rowLim = nNodes - n0;
#pragma unroll
        for (int j = 0; j < 4; ++j) {
            const int r = 4 * q + j;
            if (r < rowLim) {
                _Float16* Pr = Ph + (size_t)(n0 + r) * 64;
                _Float16* Qr = Qh + (size_t)(n0 + r) * 64;
                Pr[cn]      = (_Float16)acc0[j];
                Pr[16 + cn] = (_Float16)acc1[j];
                Pr[32 + cn] = (_Float16)acc2[j];
                Pr[48 + cn] = (_Float16)acc3[j];
                Qr[cn]      = (_Float16)acc4[j];
                Qr[16 + cn] = (_Float16)acc5[j];
                Qr[32 + cn] = (_Float16)acc6[j];
                Qr[48 + cn] = (_Float16)acc7[j];
            }
        }
    }
}

// ---------------------------------------------------------------------------
// CSR MFMA edge+aggregate (f16), TWO ADJACENT nodes per wave, R0 chassis
// (VGPR 60, no loop-carried vectors -- R1-R4: anything past the 64-VGPR
// cliff loses more TLP than it buys). R6: group-0 index loads come from the
// pre-padded fixedSrc[n*32+i] windows -- address depends only on node id, so
// they issue IN PARALLEL with the rowInfo load, collapsing the serial chain
// rowInfo->readfirstlane->idx->gather (3 L2 trips) to idx->gather (2).
// readfirstlane(deg) resolves under the gathers; deg>32 tails use the old
// rowInfo/sortedSrc path (unchanged layout).
// Pad slots replicate edge deg-1 -> unmasked max fold. f16 output rows.
// C/D layout: row=(lane>>4)*4+reg, col=lane&15 (m89-verified).
// ---------------------------------------------------------------------------
__global__ void __launch_bounds__(256) edge_agg_mfma_kernel(
    const _Float16* __restrict__ Ph, const _Float16* __restrict__ Qh,
    const int2* __restrict__ rowInfo, const int* __restrict__ sortedSrc,
    const int* __restrict__ fixedSrc,
    const float* __restrict__ W, const float* __restrict__ b,
    _Float16* __restrict__ outB, int nNodes)
{
    __shared__ u32x4 wlds[16][64];   // 16 KB: frag f (0-7 wh, 8-15 wl), per lane

    const int tid  = threadIdx.x;
    const int lane = tid & 63;
    const int cn   = lane & 15;   // A: edge slot; B/C: column
    const int q    = lane >> 4;   // quad
    const int wv   = tid >> 6;    // wave in block
    const int wave = (blockIdx.x * 256 + tid) >> 6;
    const int nw   = (gridDim.x * 256) >> 6;

    // cooperative weight-fragment init (frag f: isLo=f>=8, nt=(f&7)>>1, ks=f&1)
#pragma unroll
    for (int i = 0; i < 4; ++i) {
        const int f    = wv + i * 4;
        const int isLo = f >> 3;
        const int g    = f & 7;
        const int nt   = g >> 1;
        const int ks   = g & 1;
        u32x4 d;
#pragma unroll
        for (int p = 0; p < 4; ++p) {
            float w0 = W[(ks * 32 + q * 8 + 2 * p)     * 64 + nt * 16 + cn];
            float w1 = W[(ks * 32 + q * 8 + 2 * p + 1) * 64 + nt * 16 + cn];
            _Float16 h0, l0, h1, l1;
            split_f16(w0, h0, l0);
            split_f16(w1, h1, l1);
            d[p] = isLo ? pack_f16(l0, l1) : pack_f16(h0, h1);
        }
        wlds[f][lane] = d;
    }
    float bc[4];
#pragma unroll
    for (int nt = 0; nt < 4; ++nt) bc[nt] = b[nt * 16 + cn];
    __syncthreads();

    const u32 nClamp = (u32)(nNodes - 1);
    const int nLastN = nNodes - 1;
    const int nPairs = (nNodes + 1) >> 1;

    for (int t = wave; t < nPairs; t += nw) {
        const int n1 = 2 * t;
        const int n2 = 2 * t + 1;
        const bool has2 = (n2 < nNodes);

        // ---- issue rowInfo AND fixed group-0 index loads concurrently ----
        const int2 ri1 = rowInfo[n1];
        const int2 ri2 = has2 ? rowInfo[n2] : make_int2(ri1.x, 0);
        const size_t fb1 = (size_t)n1 * 32;
        const size_t fb2 = (size_t)(has2 ? n2 : n1) * 32;
        u32 sA1 = (u32)fixedSrc[fb1 + cn];
        u32 sB1 = (u32)fixedSrc[fb1 + 16 + cn];
        u32 sA2 = (u32)fixedSrc[fb2 + cn];
        u32 sB2 = (u32)fixedSrc[fb2 + 16 + cn];
        sA1 = min(sA1, nClamp); sB1 = min(sB1, nClamp);   // poison guard
        sA2 = min(sA2, nClamp); sB2 = min(sB2, nClamp);

        const f16x8* P1 = (const f16x8*)(Ph + (size_t)n1 * 64);
        const f16x8* P2 = (const f16x8*)(Ph + (size_t)(has2 ? n2 : n1) * 64);
        const f16x8 p1A = P1[q], p1B = P1[4 + q];
        const f16x8 p2A = P2[q], p2B = P2[4 + q];

        // ---- Q gathers (dep: fixed idx only) ----
        const f16x8* QA1 = (const f16x8*)(Qh + (size_t)sA1 * 64);
        const f16x8* QB1 = (const f16x8*)(Qh + (size_t)sB1 * 64);
        const f16x8* QA2 = (const f16x8*)(Qh + (size_t)sA2 * 64);
        const f16x8* QB2 = (const f16x8*)(Qh + (size_t)sB2 * 64);
        const f16x8 qA1a = QA1[q], qA1b = QA1[4 + q];
        const f16x8 qB1a = QB1[q], qB1b = QB1[4 + q];
        const f16x8 qA2a = QA2[q], qA2b = QA2[4 + q];
        const f16x8 qB2a = QB2[q], qB2b = QB2[4 + q];

        // ---- scalars resolve while gathers are in flight ----
        const int rs1  = __builtin_amdgcn_readfirstlane(ri1.x);
        const int deg1 = __builtin_amdgcn_readfirstlane(ri1.y);
        const int rs2  = __builtin_amdgcn_readfirstlane(ri2.x);
        const int deg2 = __builtin_amdgcn_readfirstlane(ri2.y);
        const int d1c = max(deg1, 1) - 1;
        const int d2c = max(deg2, 1) - 1;

        float m10 = -INFINITY, m11 = -INFINITY, m12 = -INFINITY, m13 = -INFINITY;
        float m20 = -INFINITY, m21 = -INFINITY, m22 = -INFINITY, m23 = -INFINITY;

        // ---- group 0 compute (unmasked fold: pads duplicate edge deg-1) ----
        if (deg1 > 0) {
            const f16x8 A00 = lrelu8(p1A + qA1a);
            const f16x8 A01 = lrelu8(p1B + qA1b);
            const f16x8 A10 = lrelu8(p1A + qB1a);
            const f16x8 A11 = lrelu8(p1B + qB1b);
#pragma unroll
            for (int nt = 0; nt < 4; ++nt) {
                const f16x8 wh0 = __builtin_bit_cast(f16x8, wlds[nt * 2][lane]);
                const f16x8 wh1 = __builtin_bit_cast(f16x8, wlds[nt * 2 + 1][lane]);
                const f16x8 wl0 = __builtin_bit_cast(f16x8, wlds[8 + nt * 2][lane]);
                const f16x8 wl1 = __builtin_bit_cast(f16x8, wlds[8 + nt * 2 + 1][lane]);
                f32x4 a; a[0] = a[1] = a[2] = a[3] = bc[nt];
                a = __builtin_amdgcn_mfma_f32_16x16x32_f16(A00, wl0, a, 0, 0, 0);
                a = __builtin_amdgcn_mfma_f32_16x16x32_f16(A00, wh0, a, 0, 0, 0);
                a = __builtin_amdgcn_mfma_f32_16x16x32_f16(A01, wl1, a, 0, 0, 0);
                a = __builtin_amdgcn_mfma_f32_16x16x32_f16(A01, wh1, a, 0, 0, 0);
                f32x4 c; c[0] = c[1] = c[2] = c[3] = bc[nt];
                c = __builtin_amdgcn_mfma_f32_16x16x32_f16(A10, wl0, c, 0, 0, 0);
                c = __builtin_amdgcn_mfma_f32_16x16x32_f16(A10, wh0, c, 0, 0, 0);
                c = __builtin_amdgcn_mfma_f32_16x16x32_f16(A11, wl1, c, 0, 0, 0);
                c = __builtin_amdgcn_mfma_f32_16x16x32_f16(A11, wh1, c, 0, 0, 0);
                float m = (nt == 0) ? m10 : (nt == 1) ? m11 : (nt == 2) ? m12 : m13;
                m = fmaxf(m, fmaxf(fmaxf(a[0], a[1]), fmaxf(a[2], a[3])));
                m = fmaxf(m, fmaxf(fmaxf(c[0], c[1]), fmaxf(c[2], c[3])));
                if (nt == 0) m10 = m; else if (nt == 1) m11 = m;
                else if (nt == 2) m12 = m; else m13 = m;
            }
        }
        if (deg2 > 0) {
            const f16x8 A00 = lrelu8(p2A + qA2a);
            const f16x8 A01 = lrelu8(p2B + qA2b);
            const f16x8 A10 = lrelu8(p2A + qB2a);
            const f16x8 A11 = lrelu8(p2B + qB2b);
#pragma unroll
            for (int nt = 0; nt < 4; ++nt) {
                const f16x8 wh0 = __builtin_bit_cast(f16x8, wlds[nt * 2][lane]);
                const f16x8 wh1 = __builtin_bit_cast(f16x8, wlds[nt * 2 + 1][lane]);
                const f16x8 wl0 = __builtin_bit_cast(f16x8, wlds[8 + nt * 2][lane]);
                const f16x8 wl1 = __builtin_bit_cast(f16x8, wlds[8 + nt * 2 + 1][lane]);
                f32x4 a; a[0] = a[1] = a[2] = a[3] = bc[nt];
                a = __builtin_amdgcn_mfma_f32_16x16x32_f16(A00, wl0, a, 0, 0, 0);
                a = __builtin_amdgcn_mfma_f32_16x16x32_f16(A00, wh0, a, 0, 0, 0);
                a = __builtin_amdgcn_mfma_f32_16x16x32_f16(A01, wl1, a, 0, 0, 0);
                a = __builtin_amdgcn_mfma_f32_16x16x32_f16(A01, wh1, a, 0, 0, 0);
                f32x4 c; c[0] = c[1] = c[2] = c[3] = bc[nt];
                c = __builtin_amdgcn_mfma_f32_16x16x32_f16(A10, wl0, c, 0, 0, 0);
                c = __builtin_amdgcn_mfma_f32_16x16x32_f16(A10, wh0, c, 0, 0, 0);
                c = __builtin_amdgcn_mfma_f32_16x16x32_f16(A11, wl1, c, 0, 0, 0);
                c = __builtin_amdgcn_mfma_f32_16x16x32_f16(A11, wh1, c, 0, 0, 0);
                float m = (nt == 0) ? m20 : (nt == 1) ? m21 : (nt == 2) ? m22 : m23;
                m = fmaxf(m, fmaxf(fmaxf(a[0], a[1]), fmaxf(a[2], a[3])));
                m = fmaxf(m, fmaxf(fmaxf(c[0], c[1]), fmaxf(c[2], c[3])));
                if (nt == 0) m20 = m; else if (nt == 1) m21 = m;
                else if (nt == 2) m22 = m; else m23 = m;
            }
        }

        // ---- tail groups >= 32 (old rowInfo/sortedSrc path, ~16% of pairs) ----
        const int gmax = max(deg1, deg2);
        for (int g0 = 32; g0 < gmax; g0 += 32) {
            u32 eA1 = (u32)sortedSrc[rs1 + min(g0 + cn,      d1c)];
            u32 eB1 = (u32)sortedSrc[rs1 + min(g0 + 16 + cn, d1c)];
            u32 eA2 = (u32)sortedSrc[rs2 + min(g0 + cn,      d2c)];
            u32 eB2 = (u32)sortedSrc[rs2 + min(g0 + 16 + cn, d2c)];
            eA1 = min(eA1, nClamp); eB1 = min(eB1, nClamp);
            eA2 = min(eA2, nClamp); eB2 = min(eB2, nClamp);
            const f16x8* EA1 = (const f16x8*)(Qh + (size_t)eA1 * 64);
            const f16x8* EB1 = (const f16x8*)(Qh + (size_t)eB1 * 64);
            const f16x8* EA2 = (const f16x8*)(Qh + (size_t)eA2 * 64);
            const f16x8* EB2 = (const f16x8*)(Qh + (size_t)eB2 * 64);
            const f16x8 gA1a = EA1[q], gA1b = EA1[4 + q];
            const f16x8 gB1a = EB1[q], gB1b = EB1[4 + q];
            const f16x8 gA2a = EA2[q], gA2b = EA2[4 + q];
            const f16x8 gB2a = EB2[q], gB2b = EB2[4 + q];

            if (g0 < deg1) {
                const f16x8 A00 = lrelu8(p1A + gA1a);
                const f16x8 A01 = lrelu8(p1B + gA1b);
                const f16x8 A10 = lrelu8(p1A + gB1a);
                const f16x8 A11 = lrelu8(p1B + gB1b);
#pragma unroll
                for (int nt = 0; nt < 4; ++nt) {
                    const f16x8 wh0 = __builtin_bit_cast(f16x8, wlds[nt * 2][lane]);
                    const f16x8 wh1 = __builtin_bit_cast(f16x8, wlds[nt * 2 + 1][lane]);
                    const f16x8 wl0 = __builtin_bit_cast(f16x8, wlds[8 + nt * 2][lane]);
                    const f16x8 wl1 = __builtin_bit_cast(f16x8, wlds[8 + nt * 2 + 1][lane]);
                    f32x4 a; a[0] = a[1] = a[2] = a[3] = bc[nt];
                    a = __builtin_amdgcn_mfma_f32_16x16x32_f16(A00, wl0, a, 0, 0, 0);
                    a = __builtin_amdgcn_mfma_f32_16x16x32_f16(A00, wh0, a, 0, 0, 0);
                    a = __builtin_amdgcn_mfma_f32_16x16x32_f16(A01, wl1, a, 0, 0, 0);
                    a = __builtin_amdgcn_mfma_f32_16x16x32_f16(A01, wh1, a, 0, 0, 0);
                    f32x4 c; c[0] = c[1] = c[2] = c[3] = bc[nt];
                    c = __builtin_amdgcn_mfma_f32_16x16x32_f16(A10, wl0, c, 0, 0, 0);
                    c = __builtin_amdgcn_mfma_f32_16x16x32_f16(A10, wh0, c, 0, 0, 0);
                    c = __builtin_amdgcn_mfma_f32_16x16x32_f16(A11, wl1, c, 0, 0, 0);
                    c = __builtin_amdgcn_mfma_f32_16x16x32_f16(A11, wh1, c, 0, 0, 0);
                    float m = (nt == 0) ? m10 : (nt == 1) ? m11 : (nt == 2) ? m12 : m13;
                    m = fmaxf(m, fmaxf(fmaxf(a[0], a[1]), fmaxf(a[2], a[3])));
                    m = fmaxf(m, fmaxf(fmaxf(c[0], c[1]), fmaxf(c[2], c[3])));
                    if (nt == 0) m10 = m; else if (nt == 1) m11 = m;
                    else if (nt == 2) m12 = m; else m13 = m;
                }
            }
            if (g0 < deg2) {
                const f16x8 A00 = lrelu8(p2A + gA2a);
                const f16x8 A01 = lrelu8(p2B + gA2b);
                const f16x8 A10 = lrelu8(p2A + gB2a);
                const f16x8 A11 = lrelu8(p2B + gB2b);
#pragma unroll
                for (int nt = 0; nt < 4; ++nt) {
                    const f16x8 wh0 = __builtin_bit_cast(f16x8, wlds[nt * 2][lane]);
                    const f16x8 wh1 = __builtin_bit_cast(f16x8, wlds[nt * 2 + 1][lane]);
                    const f16x8 wl0 = __builtin_bit_cast(f16x8, wlds[8 + nt * 2][lane]);
                    const f16x8 wl1 = __builtin_bit_cast(f16x8, wlds[8 + nt * 2 + 1][lane]);
                    f32x4 a; a[0] = a[1] = a[2] = a[3] = bc[nt];
                    a = __builtin_amdgcn_mfma_f32_16x16x32_f16(A00, wl0, a, 0, 0, 0);
                    a = __builtin_amdgcn_mfma_f32_16x16x32_f16(A00, wh0, a, 0, 0, 0);
                    a = __builtin_amdgcn_mfma_f32_16x16x32_f16(A01, wl1, a, 0, 0, 0);
                    a = __builtin_amdgcn_mfma_f32_16x16x32_f16(A01, wh1, a, 0, 0, 0);
                    f32x4 c; c[0] = c[1] = c[2] = c[3] = bc[nt];
                    c = __builtin_amdgcn_mfma_f32_16x16x32_f16(A10, wl0, c, 0, 0, 0);
                    c = __builtin_amdgcn_mfma_f32_16x16x32_f16(A10, wh0, c, 0, 0, 0);
                    c = __builtin_amdgcn_mfma_f32_16x16x32_f16(A11, wl1, c, 0, 0, 0);
                    c = __builtin_amdgcn_mfma_f32_16x16x32_f16(A11, wh1, c, 0, 0, 0);
                    float m = (nt == 0) ? m20 : (nt == 1) ? m21 : (nt == 2) ? m22 : m23;
                    m = fmaxf(m, fmaxf(fmaxf(a[0], a[1]), fmaxf(a[2], a[3])));
                    m = fmaxf(m, fmaxf(fmaxf(c[0], c[1]), fmaxf(c[2], c[3])));
                    if (nt == 0) m20 = m; else if (nt == 1) m21 = m;
                    else if (nt == 2) m22 = m; else m23 = m;
                }
            }
        }

        // cross-quad max butterflies + stores (f16)
        m10 = fmaxf(m10, __shfl_xor(m10, 16)); m10 = fmaxf(m10, __shfl_xor(m10, 32));
        m11 = fmaxf(m11, __shfl_xor(m11, 16)); m11 = fmaxf(m11, __shfl_xor(m11, 32));
        m12 = fmaxf(m12, __shfl_xor(m12, 16)); m12 = fmaxf(m12, __shfl_xor(m12, 32));
        m13 = fmaxf(m13, __shfl_xor(m13, 16)); m13 = fmaxf(m13, __shfl_xor(m13, 32));
        float sel1 = (q < 2) ? ((q == 0) ? m10 : m11) : ((q == 2) ? m12 : m13);
        outB[(size_t)n1 * 64 + q * 16 + cn] =
            (_Float16)((deg1 > 0) ? lrelu(sel1) : 0.0f);

        if (has2) {
            m20 = fmaxf(m20, __shfl_xor(m20, 16)); m20 = fmaxf(m20, __shfl_xor(m20, 32));
            m21 = fmaxf(m21, __shfl_xor(m21, 16)); m21 = fmaxf(m21, __shfl_xor(m21, 32));
            m22 = fmaxf(m22, __shfl_xor(m22, 16)); m22 = fmaxf(m22, __shfl_xor(m22, 32));
            m23 = fmaxf(m23, __shfl_xor(m23, 16)); m23 = fmaxf(m23, __shfl_xor(m23, 32));
            float sel2 = (q < 2) ? ((q == 0) ? m20 : m21) : ((q == 2) ? m22 : m23);
            outB[(size_t)n2 * 64 + q * 16 + cn] =
                (_Float16)((deg2 > 0) ? lrelu(sel2) : 0.0f);
        }
    }
}

__device__ __forceinline__ int lower_bound_i(const int* __restrict__ a, int n, int key)
{
    int lo = 0, hi = n;
    while (lo < hi) {
        int mid = (lo + hi) >> 1;
        if (a[mid] < key) lo = mid + 1; else hi = mid;
    }
    return lo;
}

// PPARTS blocks per graph (1024 blocks, streaming-BW bound), f16 input.
__global__ void __launch_bounds__(256) pool_kernel(
    const _Float16* __restrict__ Bh, const int* __restrict__ batch,
    float* __restrict__ gpart, int nNodes)
{
    const int gid  = blockIdx.x / PPARTS;
    const int part = blockIdx.x % PPARTS;
    const int c    = threadIdx.x & 63;
    const int wid  = threadIdx.x >> 6;

    const int s = lower_bound_i(batch, nNodes, gid);
    const int e = lower_bound_i(batch, nNodes, gid + 1);
    const int len = e - s;
    const int ps = s + (len * part) / PPARTS;
    const int pe = s + (len * (part + 1)) / PPARTS;

    float sum = 0.f, mx = -INFINITY;
    for (int n = ps + wid; n < pe; n += 4) {
        float v = (float)Bh[(size_t)n * 64 + c];
        sum += v;
        mx = fmaxf(mx, v);
    }
    __shared__ float ssum[4][64];
    __shared__ float smax[4][64];
    ssum[wid][c] = sum;
    smax[wid][c] = mx;
    __syncthreads();
    if (wid == 0) {
        sum = (ssum[0][c] + ssum[1][c]) + (ssum[2][c] + ssum[3][c]);
        mx  = fmaxf(fmaxf(smax[0][c], smax[1][c]), fmaxf(smax[2][c], smax[3][c]));
        float* row = gpart + (size_t)blockIdx.x * 132;
        row[c]      = sum;
        row[64 + c] = mx;
        if (c == 0) row[128] = (float)(pe - ps);
    }
}

// One wave per graph: combine PPARTS pool partials, then classifier head.
__global__ void __launch_bounds__(64) cls_kernel(
    const float* __restrict__ gpart,
    const float* __restrict__ Wc1, const float* __restrict__ bc1,
    const float* __restrict__ Wc2, const float* __restrict__ bc2,
    float* __restrict__ out)
{
    __shared__ float g[128];
    const int gid = blockIdx.x;
    const int c   = threadIdx.x;

    float s = 0.f, m = -INFINITY, cnt = 0.f;
#pragma unroll
    for (int p = 0; p < PPARTS; ++p) {
        const float* row = gpart + (size_t)(gid * PPARTS + p) * 132;
        s += row[c];
        m = fmaxf(m, row[64 + c]);
        cnt += row[128];
    }
    g[c]      = s / fmaxf(cnt, 1.0f);
    g[64 + c] = (cnt > 0.f) ? m : 0.0f;
    __syncthreads();

    float t = bc1[c];
#pragma unroll 8
    for (int k = 0; k < 128; ++k) t = fmaf(g[k], Wc1[k * 64 + c], t);
    t = lrelu(t);
    float p = t * Wc2[c];
#pragma unroll
    for (int off = 32; off > 0; off >>= 1) p += __shfl_down(p, off);
    if (c == 0) out[gid] = p + bc2[0];
}

static inline size_t align_up(size_t v, size_t a) { return (v + a - 1) & ~(a - 1); }

extern "C" void kernel_launch(void* const* d_in, const int* in_sizes, int n_in,
                              void* d_out, int out_size, void* d_ws, size_t ws_size,
                              hipStream_t stream)
{
    const float* x     = (const float*)d_in[0];
    const int*   ei    = (const int*)d_in[1];
    const int*   batch = (const int*)d_in[2];
    const float* W1  = (const float*)d_in[3];
    const float* b1  = (const float*)d_in[4];
    const float* W2  = (const float*)d_in[5];
    const float* b2  = (const float*)d_in[6];
    const float* W3  = (const float*)d_in[7];
    const float* b3  = (const float*)d_in[8];
    const float* W4  = (const float*)d_in[9];
    const float* b4  = (const float*)d_in[10];
    const float* Wc1 = (const float*)d_in[11];
    const float* bc1 = (const float*)d_in[12];
    const float* Wc2 = (const float*)d_in[13];
    const float* bc2 = (const float*)d_in[14];
    float* out = (float*)d_out;

    const int nNodes  = in_sizes[0] / 6;
    const int E       = in_sizes[1] / 2;
    const int nGraphs = out_size;
    const int* srcI = ei;
    const int* dstI = ei + E;
    const int nBuck = (nNodes + NPB - 1) / NPB;
    const int nCntB = (E + EPB - 1) / EPB;

    // workspace carve-up (256B-aligned)
    char* wsp = (char*)d_ws;
    size_t off = 0;
    int*  cursor    = (int*)(wsp + off);   off = align_up(off + (size_t)MAXBUCK * 8 * 4, 256);
    int2* rowInfo   = (int2*)(wsp + off);  off = align_up(off + (size_t)nNodes * 8, 256);
    int*  sortedSrc = (int*)(wsp + off);   off = align_up(off + (size_t)nBuck * CAP * 4, 256);
    int*  fixedSrc  = (int*)(wsp + off);   off = align_up(off + (size_t)nNodes * 32 * 4, 256);
    u32*  pairW     = (u32*)(wsp + off);   off = align_up(off + (size_t)nBuck * 8 * SUBCAP * 4, 256);
    const size_t nFeat = (size_t)nNodes * 64;
    _Float16* Ph   = (_Float16*)(wsp + off);  off = align_up(off + nFeat * 2, 256);
    _Float16* Qh   = (_Float16*)(wsp + off);  off = align_up(off + nFeat * 2, 256);
    _Float16* B1h  = (_Float16*)(wsp + off);  off = align_up(off + nFeat * 2, 256);
    _Float16* B2h  = (_Float16*)(wsp + off);  off = align_up(off + nFeat * 2, 256);
    float*    gpart= (float*)(wsp + off);     off = align_up(off + (size_t)nGraphs * PPARTS * 132 * 4, 256);
    (void)ws_size;

    // ---- CSR build (vectorized scatter, privatized hist) + conv1 transform ----
    (void)hipMemsetAsync(cursor, 0, (size_t)nBuck * 8 * 4, stream);
    scatter_xform1_kernel<<<nCntB + XF1B, 256, 0, stream>>>(
        srcI, dstI, cursor, pairW, E, nNodes, nBuck, nCntB, x, W1, b1, Ph, Qh);
    bucket_sort_kernel<<<nBuck, 256, 0, stream>>>(pairW, cursor, rowInfo,
                                                  sortedSrc, fixedSrc, nNodes);

    // ---- conv1 edge+agg ----
    edge_agg_mfma_kernel<<<2048, 256, 0, stream>>>(Ph, Qh, rowInfo, sortedSrc,
                                                   fixedSrc, W2, b2, B1h, nNodes);
    // ---- conv2: node transform on the matrix pipe ----
    const int nGrp   = (nNodes + 15) >> 4;          // 16 nodes per wave-group
    const int xf2Blk = (nGrp + 3) >> 2;             // 4 waves per block
    node_xform2_mfma_kernel<<<xf2Blk, 256, 0, stream>>>(B1h, W3, b3, Ph, Qh,
                                                        nNodes);
    edge_agg_mfma_kernel<<<2048, 256, 0, stream>>>(Ph, Qh, rowInfo, sortedSrc,
                                                   fixedSrc, W4, b4, B2h, nNodes);

    // ---- pooling + classifier head ----
    pool_kernel<<<nGraphs * PPARTS, 256, 0, stream>>>(B2h, batch, gpart, nNodes);
    cls_kernel<<<nGraphs, 64, 0, stream>>>(gpart, Wc1, bc1, Wc2, bc2, out);
}